// Round 1
// baseline (706.098 us; speedup 1.0000x reference)
//
#include <hip/hip_runtime.h>
#include <stdint.h>

// Problem constants
#define B_    64
#define N_    512
#define DIM_  256
#define H_    8
#define DH_   64
#define INNER_ 512

typedef __attribute__((ext_vector_type(8))) short bf16x8;
typedef __attribute__((ext_vector_type(4))) float f32x4;
typedef __attribute__((ext_vector_type(4))) short s16x4;

typedef const __attribute__((address_space(1))) void* gas_ptr;
typedef __attribute__((address_space(3))) void* las_ptr;

__device__ __forceinline__ short f2bf(float f) {
  unsigned int u = __float_as_uint(f);
  u += 0x7fffu + ((u >> 16) & 1u);          // RNE
  return (short)(u >> 16);
}
__device__ __forceinline__ float bf2f(short s) {
  return __uint_as_float(((unsigned int)(unsigned short)s) << 16);
}
__device__ __forceinline__ void cp16(const void* g, void* l) {
  __builtin_amdgcn_global_load_lds((gas_ptr)g, (las_ptr)l, 16, 0, 0);
}
__device__ __forceinline__ f32x4 mfma16(bf16x8 a, bf16x8 b, f32x4 c) {
  return __builtin_amdgcn_mfma_f32_16x16x32_bf16(a, b, c, 0, 0, 0);
}

// ---------------------------------------------------------------------------
// Prep: fp32 -> bf16 edge conversions (+ scaled bias copy, float mask).
//  Wt1[2048][256] bf16: rows 0..511=Wq cols, 512..1535=Wkv cols, 1536..2047=Wg
//  WoT[256][512] bf16 = Wo^T
//  xb[32768*256] bf16 = x flat
//  biasS[h][i][j] fp32 = bias * log2(e)   (same layout, exp2-based softmax)
//  maskF[b*512+j] fp32 = mask ? 1 : 0
// ---------------------------------------------------------------------------
#define PREP_WT1  (2048 * 256)
#define PREP_WOT  (256 * 512)
#define PREP_X    (32768 * 256)
#define PREP_BIAS (8 * 512 * 512)
#define PREP_MASK (64 * 512)
#define PREP_TOT  (PREP_WT1 + PREP_WOT + PREP_X + PREP_BIAS + PREP_MASK)

__global__ void prep_k(const float* __restrict__ x,
                       const float* __restrict__ Wq, const float* __restrict__ Wkv,
                       const float* __restrict__ Wg, const float* __restrict__ Wo,
                       const float* __restrict__ bias, const int* __restrict__ mask,
                       short* __restrict__ Wt1, short* __restrict__ WoT,
                       short* __restrict__ xb, float* __restrict__ biasS,
                       float* __restrict__ maskF)
{
  const int idx = blockIdx.x * 256 + threadIdx.x;
  if (idx < PREP_WT1) {
    const int n = idx >> 8, k = idx & 255;
    float v;
    if (n < 512)        v = Wq[k * 512 + n];
    else if (n < 1536)  v = Wkv[k * 1024 + (n - 512)];   // K cols then V cols
    else                v = Wg[k * 512 + (n - 1536)];
    Wt1[idx] = f2bf(v);
  } else if (idx < PREP_WT1 + PREP_WOT) {
    const int j = idx - PREP_WT1;
    const int n = j >> 9, k = j & 511;
    WoT[j] = f2bf(Wo[k * 256 + n]);
  } else if (idx < PREP_WT1 + PREP_WOT + PREP_X) {
    const int j = idx - (PREP_WT1 + PREP_WOT);
    xb[j] = f2bf(x[j]);
  } else if (idx < PREP_WT1 + PREP_WOT + PREP_X + PREP_BIAS) {
    const int j = idx - (PREP_WT1 + PREP_WOT + PREP_X);
    biasS[j] = bias[j] * 1.4426950408889634f;            // coalesced scaled copy
  } else if (idx < PREP_TOT) {
    const int j = idx - (PREP_WT1 + PREP_WOT + PREP_X + PREP_BIAS);
    maskF[j] = mask[j] ? 1.0f : 0.0f;
  }
}

// ---------------------------------------------------------------------------
// GEMM1: C = xb[32768,256] @ Wt1^T  (N=2048 fused Q|K|V|G), all bf16.
// Grid (16 n-tiles fastest, 256 m-tiles): consecutive blocks share the X
// row-slice (64KB, L2-hot) and sweep Wt (1MB, fits L2).
// ---------------------------------------------------------------------------
__global__ __launch_bounds__(256, 2) void gemm_qkvg(
    const short* __restrict__ X, const short* __restrict__ Wt,
    const float* __restrict__ bg,
    short* __restrict__ Q, short* __restrict__ Kb,
    short* __restrict__ Vt, short* __restrict__ G)
{
  __shared__ __align__(16) short As[128 * 32];
  __shared__ __align__(16) short Bs[128 * 32];
  const int tid = threadIdx.x;
  const int w = tid >> 6, lane = tid & 63;
  const int m = lane & 15, q = lane >> 4;
  const int n0 = blockIdx.x * 128, m0 = blockIdx.y * 128;
  const int ric = lane >> 2, cslot = lane & 3;
  const int csw = cslot ^ ((ric >> 1) & 3);
  const int wr = (w >> 1) * 64, wc = (w & 1) * 64;
  const int rsw = (m >> 1) & 3;
  f32x4 acc[4][4] = {};
  for (int k0 = 0; k0 < DIM_; k0 += 32) {
    __syncthreads();
#pragma unroll
    for (int s = 0; s < 2; ++s) {
      const int rr = w * 32 + s * 16;
      cp16(X  + (size_t)(m0 + rr + ric) * DIM_ + (k0 + csw * 8), &As[rr * 32]);
      cp16(Wt + (size_t)(n0 + rr + ric) * DIM_ + (k0 + csw * 8), &Bs[rr * 32]);
    }
    __syncthreads();
    bf16x8 af[4], bfv[4];
#pragma unroll
    for (int t = 0; t < 4; ++t) {
      af[t]  = *(const bf16x8*)&As[(wr + t * 16 + m) * 32 + ((q ^ rsw) * 8)];
      bfv[t] = *(const bf16x8*)&Bs[(wc + t * 16 + m) * 32 + ((q ^ rsw) * 8)];
    }
#pragma unroll
    for (int ti = 0; ti < 4; ++ti)
#pragma unroll
      for (int tj = 0; tj < 4; ++tj)
        acc[ti][tj] = mfma16(af[ti], bfv[tj], acc[ti][tj]);
  }
  const int region = blockIdx.x >> 2;           // 0=Q 1=K 2=V 3=G
  const int cb = (n0 & 511) + wc;
#pragma unroll
  for (int ti = 0; ti < 4; ++ti) {
    const int mgb = m0 + wr + ti * 16 + q * 4;
    const int b = mgb >> 9, n = mgb & 511;
#pragma unroll
    for (int tj = 0; tj < 4; ++tj) {
      const int c = cb + tj * 16 + m;
      const int h = c >> 6, d = c & 63;
      if (region == 2) {                        // V -> transposed [B,H,DH,N]
        s16x4 st;
#pragma unroll
        for (int r = 0; r < 4; ++r) st[r] = f2bf(acc[ti][tj][r]);
        *(s16x4*)&Vt[((size_t)(b * 8 + h) * 64 + d) * 512 + n] = st;
      } else if (region == 0) {
#pragma unroll
        for (int r = 0; r < 4; ++r)
          Q[((size_t)(b * 8 + h) * 512 + (n + r)) * 64 + d] = f2bf(acc[ti][tj][r]);
      } else if (region == 1) {
#pragma unroll
        for (int r = 0; r < 4; ++r)
          Kb[((size_t)(b * 8 + h) * 512 + (n + r)) * 64 + d] = f2bf(acc[ti][tj][r]);
      } else {                                  // gates = x@Wg + bg
        const float bgv = bg[c];
#pragma unroll
        for (int r = 0; r < 4; ++r)
          G[(size_t)(mgb + r) * 512 + c] = f2bf(acc[ti][tj][r] + bgv);
      }
    }
  }
}

// ---------------------------------------------------------------------------
// Attention, flash-style with TRANSPOSED score MFMA (S^T = K·Q^T).
// NEW: one block per (b,h): 1024 threads / 16 waves, 512 Q rows per block.
//  - per-wave code unchanged (32 rows/wave), but the block consumes each
//    staged 16KB K/V chunk with 4x the compute -> staging amortized 4x
//  - K/V fetched exactly once per (b,h) (old iq-split re-fetched 4x)
//  - LDS = Ks 16K + Vs 16K + P 16x2K = 64KB -> 2 blocks/CU = 32 waves/CU
//    (100% occupancy at VGPR=64, enforced by __launch_bounds__(1024,8))
//  - staging: waves 0-7 stage K (8 rows each), waves 8-15 stage V
// ---------------------------------------------------------------------------
__global__ __launch_bounds__(1024, 8) void attn_k(
    const short* __restrict__ Q, const short* __restrict__ K,
    const short* __restrict__ Vt, const float* __restrict__ biasS,
    const float* __restrict__ maskF, short* __restrict__ G)
{
  __shared__ __align__(16) short Ks[2][64 * 64];    // [j][d], xor-swizzled 8-chunks
  __shared__ __align__(16) short Vs[2][64 * 64];    // [d][j], xor-swizzled
  __shared__ __align__(16) short Pall[16][16 * 64]; // per-wave, reused per i-tile
  const int tid = threadIdx.x;
  const int w = tid >> 6, lane = tid & 63;
  const int m = lane & 15, q = lane >> 4;
  const int m7 = m & 7;
  const int b = blockIdx.x, h = blockIdx.y;
  const int i0w = w * 32;                          // this wave's first Q row
  const size_t bh = (size_t)b * 8 + h;
  const short* Qp = Q + (bh * 512 + i0w) * 64;
  const short* Kp = K + bh * 512 * 64;
  const short* Vp = Vt + bh * 64 * 512;
  const float* mkp = maskF + b * 512;
  short* Ps = Pall[w];

  const int srow = lane >> 3;                      // staging row in 8-row group
  const int gchunk = (lane & 7) ^ (srow & 7);      // global 8-short chunk to fetch
  const int sgrp = (w & 7) * 8;                    // this wave's 8-row stage group
  const int isV = w >> 3;                          // waves 0-7: K, 8-15: V

  // Q frags (B-operand): lane holds Q[i=m][d=q*8+jj]
  bf16x8 qf[2][2];
#pragma unroll
  for (int it = 0; it < 2; ++it) {
    qf[it][0] = *(const bf16x8*)&Qp[(it * 16 + m) * 64 + q * 8];
    qf[it][1] = *(const bf16x8*)&Qp[(it * 16 + m) * 64 + 32 + q * 8];
  }
  float miF[2];
#pragma unroll
  for (int it = 0; it < 2; ++it) miF[it] = mkp[i0w + it * 16 + m];

  // stage chunk 0 (one cp16 per wave)
  if (!isV) cp16(Kp + (size_t)(sgrp + srow) * 64 + gchunk * 8, &Ks[0][sgrp * 64]);
  else      cp16(Vp + (size_t)(sgrp + srow) * 512 + gchunk * 8, &Vs[0][sgrp * 64]);

  f32x4 o[2][4] = {};
  float l[2] = {0.f, 0.f};
  __syncthreads();                                 // chunk 0 staged

  const float SCL = 0.125f * 1.4426950408889634f;  // scale * log2(e)
  for (int c = 0; c < 8; ++c) {
    const int p = c & 1;
    if (c < 7) {                                   // prefetch next chunk
      const int jn = (c + 1) * 64;
      if (!isV) cp16(Kp + (size_t)(jn + sgrp + srow) * 64 + gchunk * 8,
                     &Ks[p ^ 1][sgrp * 64]);
      else      cp16(Vp + (size_t)(sgrp + srow) * 512 + jn + gchunk * 8,
                     &Vs[p ^ 1][sgrp * 64]);
    }
    // mask (f32x4 per jt): j = c*64 + jt*16 + q*4 + r
    f32x4 mjf[4];
#pragma unroll
    for (int jt = 0; jt < 4; ++jt)
      mjf[jt] = *(const f32x4*)&mkp[c * 64 + jt * 16 + q * 4];

    // QK^T (transposed): S^T tile = mfma(A=K rows j, B=Q cols i)
    // lane holds S[i = it*16+m][j = c*64 + jt*16 + q*4 + r]
    f32x4 s[2][4];
#pragma unroll
    for (int jt = 0; jt < 4; ++jt) {
      const bf16x8 ka = *(const bf16x8*)&Ks[p][(jt * 16 + m) * 64 + ((q ^ m7) * 8)];
      const bf16x8 kb = *(const bf16x8*)&Ks[p][(jt * 16 + m) * 64 + (((4 + q) ^ m7) * 8)];
#pragma unroll
      for (int it = 0; it < 2; ++it) {
        f32x4 a = {};
        a = mfma16(ka, qf[it][0], a);
        s[it][jt] = mfma16(kb, qf[it][1], a);
      }
    }
#pragma unroll
    for (int it = 0; it < 2; ++it) {
      // bias (fp32, prescaled by log2e, original [h][i][j] layout)
      const float* bp = biasS + ((size_t)h * 512 + i0w + it * 16 + m) * 512 + c * 64;
      f32x4 bv[4];
#pragma unroll
      for (int jt = 0; jt < 4; ++jt)
        bv[jt] = *(const f32x4*)&bp[jt * 16 + q * 4];
      // softmax terms -> packed b64 P writes (4 consecutive j per lane)
#pragma unroll
      for (int jt = 0; jt < 4; ++jt) {
        s16x4 st;
#pragma unroll
        for (int r = 0; r < 4; ++r) {
          const float v = fmaf(s[it][jt][r], SCL, bv[jt][r]);
          float e = exp2f(v) * mjf[jt][r];
          e = (miF[it] != 0.0f) ? e : 1.0f;        // fully-masked row -> uniform
          const unsigned u = __float_as_uint(e);
          st[r] = (short)(u >> 16);                // trunc pack
          l[it] += __uint_as_float(u & 0xffff0000u); // == stored P
        }
        *(s16x4*)&Ps[m * 64 + (((jt * 2 + (q >> 1)) ^ m7) * 8) + (q & 1) * 4] = st;
      }
      // PV for this i-tile: A = P rows i, B = V^T cols d
      const bf16x8 pa = *(const bf16x8*)&Ps[m * 64 + ((q ^ m7) * 8)];
      const bf16x8 pb = *(const bf16x8*)&Ps[m * 64 + (((4 + q) ^ m7) * 8)];
#pragma unroll
      for (int dt = 0; dt < 4; ++dt) {
        const bf16x8 va = *(const bf16x8*)&Vs[p][(dt * 16 + m) * 64 + ((q ^ m7) * 8)];
        const bf16x8 vb = *(const bf16x8*)&Vs[p][(dt * 16 + m) * 64 + (((4 + q) ^ m7) * 8)];
        o[it][dt] = mfma16(pa, va, o[it][dt]);
        o[it][dt] = mfma16(pb, vb, o[it][dt]);
      }
    }
    __syncthreads();  // Ks/Vs[p] reads done; prefetch (p^1) drained
  }

  // ---- epilogue: reduce l over q-lanes (lane holds row i = it*16+m) ----
#pragma unroll
  for (int it = 0; it < 2; ++it) {
    float t = l[it];
    t += __shfl_xor(t, 16, 64);
    t += __shfl_xor(t, 32, 64);
    l[it] = 1.0f / t;
  }
  const int colb = h * 64;
#pragma unroll
  for (int it = 0; it < 2; ++it) {
    // broadcast 1/l to o's row layout (row = q*4+r): pull from lane m = q*4+r
    float lr[4];
#pragma unroll
    for (int r = 0; r < 4; ++r) lr[r] = __shfl(l[it], q * 4 + r, 16);
#pragma unroll
    for (int dt = 0; dt < 4; ++dt)
#pragma unroll
      for (int r = 0; r < 4; ++r) {
        const int row = i0w + it * 16 + q * 4 + r;
        const size_t addr = ((size_t)b * 512 + row) * 512 + colb + dt * 16 + m;
        const float gate = bf2f(G[addr]);
        G[addr] = f2bf(o[it][dt][r] * lr[r] * gate);
      }
  }
}

// ---------------------------------------------------------------------------
// GEMM3: out = OG[32768,512] @ Wo + bo   (B^T = WoT[256][512]); fp32 output.
// Grid (2 n-tiles fastest, 256 m-tiles).
// ---------------------------------------------------------------------------
__global__ __launch_bounds__(256, 2) void gemm_og(
    const short* __restrict__ A, const short* __restrict__ Bt,
    const float* __restrict__ bo, float* __restrict__ out)
{
  __shared__ __align__(16) short As[128 * 32];
  __shared__ __align__(16) short Bs[128 * 32];
  const int tid = threadIdx.x;
  const int w = tid >> 6, lane = tid & 63;
  const int m = lane & 15, q = lane >> 4;
  const int n0 = blockIdx.x * 128, m0 = blockIdx.y * 128;
  const int ric = lane >> 2, cslot = lane & 3;
  const int csw = cslot ^ ((ric >> 1) & 3);
  const int wr = (w >> 1) * 64, wc = (w & 1) * 64;
  const int rsw = (m >> 1) & 3;
  f32x4 acc[4][4] = {};
  for (int k0 = 0; k0 < INNER_; k0 += 32) {
    __syncthreads();
#pragma unroll
    for (int s = 0; s < 2; ++s) {
      const int rr = w * 32 + s * 16;
      cp16(A  + (size_t)(m0 + rr + ric) * INNER_ + (k0 + csw * 8), &As[rr * 32]);
      cp16(Bt + (size_t)(n0 + rr + ric) * INNER_ + (k0 + csw * 8), &Bs[rr * 32]);
    }
    __syncthreads();
    bf16x8 af[4], bfv[4];
#pragma unroll
    for (int t = 0; t < 4; ++t) {
      af[t]  = *(const bf16x8*)&As[(wr + t * 16 + m) * 32 + ((q ^ rsw) * 8)];
      bfv[t] = *(const bf16x8*)&Bs[(wc + t * 16 + m) * 32 + ((q ^ rsw) * 8)];
    }
#pragma unroll
    for (int ti = 0; ti < 4; ++ti)
#pragma unroll
      for (int tj = 0; tj < 4; ++tj)
        acc[ti][tj] = mfma16(af[ti], bfv[tj], acc[ti][tj]);
  }
#pragma unroll
  for (int ti = 0; ti < 4; ++ti) {
    const int row = m0 + wr + ti * 16 + q * 4;
#pragma unroll
    for (int tj = 0; tj < 4; ++tj) {
      const int c = n0 + wc + tj * 16 + m;
      const float bov = bo[c];
#pragma unroll
      for (int r = 0; r < 4; ++r)
        out[(size_t)(row + r) * 256 + c] = acc[ti][tj][r] + bov;
    }
  }
}

// ---------------------------------------------------------------------------
extern "C" void kernel_launch(void* const* d_in, const int* in_sizes, int n_in,
                              void* d_out, int out_size, void* d_ws, size_t ws_size,
                              hipStream_t stream)
{
  (void)in_sizes; (void)n_in; (void)out_size; (void)ws_size;
  const float* x    = (const float*)d_in[0];
  const int*   mask = (const int*)d_in[1];
  const float* bias = (const float*)d_in[2];
  const float* Wq   = (const float*)d_in[3];
  const float* Wkv  = (const float*)d_in[4];
  const float* Wo   = (const float*)d_in[5];
  const float* bo   = (const float*)d_in[6];
  const float* Wg   = (const float*)d_in[7];
  const float* bg   = (const float*)d_in[8];
  float* out = (float*)d_out;

  char* ws = (char*)d_ws;
  size_t off = 0;
  short* Wt1   = (short*)(ws + off); off += (size_t)2048 * 256 * 2;         // 1.0 MiB
  short* WoT   = (short*)(ws + off); off += (size_t)256 * 512 * 2;          // 0.25 MiB
  short* xb    = (short*)(ws + off); off += (size_t)32768 * 256 * 2;        // 16 MiB
  short* Qb    = (short*)(ws + off); off += (size_t)B_ * H_ * N_ * DH_ * 2; // 32 MiB
  short* Kb    = (short*)(ws + off); off += (size_t)B_ * H_ * N_ * DH_ * 2; // 32 MiB
  short* Vt    = (short*)(ws + off); off += (size_t)B_ * H_ * DH_ * N_ * 2; // 32 MiB
  short* G     = (short*)(ws + off); off += (size_t)B_ * N_ * INNER_ * 2;   // 32 MiB
  float* biasS = (float*)(ws + off); off += (size_t)H_ * N_ * N_ * 4;       // 8 MiB
  float* maskF = (float*)(ws + off); off += (size_t)B_ * N_ * 4;            // 128 KiB

  prep_k<<<(PREP_TOT + 255) / 256, 256, 0, stream>>>(x, Wq, Wkv, Wg, Wo, bias, mask,
                                                     Wt1, WoT, xb, biasS, maskF);
  gemm_qkvg<<<dim3(16, 256), 256, 0, stream>>>(xb, Wt1, bg, Qb, Kb, Vt, G);
  attn_k<<<dim3(64, 8), 1024, 0, stream>>>(Qb, Kb, Vt, biasS, maskF, G);
  gemm_og<<<dim3(2, 256), 256, 0, stream>>>(G, WoT, bo, out);
}

// Round 2
// 472.580 us; speedup vs baseline: 1.4941x; 1.4941x over previous
//
#include <hip/hip_runtime.h>
#include <stdint.h>

// Problem constants
#define B_    64
#define N_    512
#define DIM_  256
#define H_    8
#define DH_   64
#define INNER_ 512

typedef __attribute__((ext_vector_type(8))) short bf16x8;
typedef __attribute__((ext_vector_type(4))) float f32x4;
typedef __attribute__((ext_vector_type(4))) short s16x4;

typedef const __attribute__((address_space(1))) void* gas_ptr;
typedef __attribute__((address_space(3))) void* las_ptr;

__device__ __forceinline__ short f2bf(float f) {
  unsigned int u = __float_as_uint(f);
  u += 0x7fffu + ((u >> 16) & 1u);          // RNE
  return (short)(u >> 16);
}
__device__ __forceinline__ float bf2f(short s) {
  return __uint_as_float(((unsigned int)(unsigned short)s) << 16);
}
__device__ __forceinline__ void cp16(const void* g, void* l) {
  __builtin_amdgcn_global_load_lds((gas_ptr)g, (las_ptr)l, 16, 0, 0);
}
__device__ __forceinline__ f32x4 mfma16(bf16x8 a, bf16x8 b, f32x4 c) {
  return __builtin_amdgcn_mfma_f32_16x16x32_bf16(a, b, c, 0, 0, 0);
}

// ---------------------------------------------------------------------------
// Prep: fp32 -> bf16 edge conversions (+ scaled bias copy, float mask).
//  Wt1[2048][256] bf16: rows 0..511=Wq cols, 512..1535=Wkv cols, 1536..2047=Wg
//  WoT[256][512] bf16 = Wo^T
//  xb[32768*256] bf16 = x flat
//  biasS[h][i][j] fp32 = bias * log2(e)   (same layout, exp2-based softmax)
//  maskF[b*512+j] fp32 = mask ? 1 : 0
// ---------------------------------------------------------------------------
#define PREP_WT1  (2048 * 256)
#define PREP_WOT  (256 * 512)
#define PREP_X    (32768 * 256)
#define PREP_BIAS (8 * 512 * 512)
#define PREP_MASK (64 * 512)
#define PREP_TOT  (PREP_WT1 + PREP_WOT + PREP_X + PREP_BIAS + PREP_MASK)

__global__ void prep_k(const float* __restrict__ x,
                       const float* __restrict__ Wq, const float* __restrict__ Wkv,
                       const float* __restrict__ Wg, const float* __restrict__ Wo,
                       const float* __restrict__ bias, const int* __restrict__ mask,
                       short* __restrict__ Wt1, short* __restrict__ WoT,
                       short* __restrict__ xb, float* __restrict__ biasS,
                       float* __restrict__ maskF)
{
  const int idx = blockIdx.x * 256 + threadIdx.x;
  if (idx < PREP_WT1) {
    const int n = idx >> 8, k = idx & 255;
    float v;
    if (n < 512)        v = Wq[k * 512 + n];
    else if (n < 1536)  v = Wkv[k * 1024 + (n - 512)];   // K cols then V cols
    else                v = Wg[k * 512 + (n - 1536)];
    Wt1[idx] = f2bf(v);
  } else if (idx < PREP_WT1 + PREP_WOT) {
    const int j = idx - PREP_WT1;
    const int n = j >> 9, k = j & 511;
    WoT[j] = f2bf(Wo[k * 256 + n]);
  } else if (idx < PREP_WT1 + PREP_WOT + PREP_X) {
    const int j = idx - (PREP_WT1 + PREP_WOT);
    xb[j] = f2bf(x[j]);
  } else if (idx < PREP_WT1 + PREP_WOT + PREP_X + PREP_BIAS) {
    const int j = idx - (PREP_WT1 + PREP_WOT + PREP_X);
    biasS[j] = bias[j] * 1.4426950408889634f;            // coalesced scaled copy
  } else if (idx < PREP_TOT) {
    const int j = idx - (PREP_WT1 + PREP_WOT + PREP_X + PREP_BIAS);
    maskF[j] = mask[j] ? 1.0f : 0.0f;
  }
}

// ---------------------------------------------------------------------------
// GEMM1: C = xb[32768,256] @ Wt1^T  (N=2048 fused Q|K|V|G), all bf16.
// Grid (16 n-tiles fastest, 256 m-tiles): consecutive blocks share the X
// row-slice (64KB, L2-hot) and sweep Wt (1MB, fits L2).
// ---------------------------------------------------------------------------
__global__ __launch_bounds__(256, 2) void gemm_qkvg(
    const short* __restrict__ X, const short* __restrict__ Wt,
    const float* __restrict__ bg,
    short* __restrict__ Q, short* __restrict__ Kb,
    short* __restrict__ Vt, short* __restrict__ G)
{
  __shared__ __align__(16) short As[128 * 32];
  __shared__ __align__(16) short Bs[128 * 32];
  const int tid = threadIdx.x;
  const int w = tid >> 6, lane = tid & 63;
  const int m = lane & 15, q = lane >> 4;
  const int n0 = blockIdx.x * 128, m0 = blockIdx.y * 128;
  const int ric = lane >> 2, cslot = lane & 3;
  const int csw = cslot ^ ((ric >> 1) & 3);
  const int wr = (w >> 1) * 64, wc = (w & 1) * 64;
  const int rsw = (m >> 1) & 3;
  f32x4 acc[4][4] = {};
  for (int k0 = 0; k0 < DIM_; k0 += 32) {
    __syncthreads();
#pragma unroll
    for (int s = 0; s < 2; ++s) {
      const int rr = w * 32 + s * 16;
      cp16(X  + (size_t)(m0 + rr + ric) * DIM_ + (k0 + csw * 8), &As[rr * 32]);
      cp16(Wt + (size_t)(n0 + rr + ric) * DIM_ + (k0 + csw * 8), &Bs[rr * 32]);
    }
    __syncthreads();
    bf16x8 af[4], bfv[4];
#pragma unroll
    for (int t = 0; t < 4; ++t) {
      af[t]  = *(const bf16x8*)&As[(wr + t * 16 + m) * 32 + ((q ^ rsw) * 8)];
      bfv[t] = *(const bf16x8*)&Bs[(wc + t * 16 + m) * 32 + ((q ^ rsw) * 8)];
    }
#pragma unroll
    for (int ti = 0; ti < 4; ++ti)
#pragma unroll
      for (int tj = 0; tj < 4; ++tj)
        acc[ti][tj] = mfma16(af[ti], bfv[tj], acc[ti][tj]);
  }
  const int region = blockIdx.x >> 2;           // 0=Q 1=K 2=V 3=G
  const int cb = (n0 & 511) + wc;
#pragma unroll
  for (int ti = 0; ti < 4; ++ti) {
    const int mgb = m0 + wr + ti * 16 + q * 4;
    const int b = mgb >> 9, n = mgb & 511;
#pragma unroll
    for (int tj = 0; tj < 4; ++tj) {
      const int c = cb + tj * 16 + m;
      const int h = c >> 6, d = c & 63;
      if (region == 2) {                        // V -> transposed [B,H,DH,N]
        s16x4 st;
#pragma unroll
        for (int r = 0; r < 4; ++r) st[r] = f2bf(acc[ti][tj][r]);
        *(s16x4*)&Vt[((size_t)(b * 8 + h) * 64 + d) * 512 + n] = st;
      } else if (region == 0) {
#pragma unroll
        for (int r = 0; r < 4; ++r)
          Q[((size_t)(b * 8 + h) * 512 + (n + r)) * 64 + d] = f2bf(acc[ti][tj][r]);
      } else if (region == 1) {
#pragma unroll
        for (int r = 0; r < 4; ++r)
          Kb[((size_t)(b * 8 + h) * 512 + (n + r)) * 64 + d] = f2bf(acc[ti][tj][r]);
      } else {                                  // gates = x@Wg + bg
        const float bgv = bg[c];
#pragma unroll
        for (int r = 0; r < 4; ++r)
          G[(size_t)(mgb + r) * 512 + c] = f2bf(acc[ti][tj][r] + bgv);
      }
    }
  }
}

// ---------------------------------------------------------------------------
// Attention, flash-style with TRANSPOSED score MFMA (S^T = K·Q^T).
// Round-0 structure (256 thr, 40KB LDS, 4 blocks/CU) + three changes:
//  1. bias/mask register loads issued BEFORE the cp16 prefetch: vmcnt is
//     FIFO, so waiting on bias no longer drains the K/V prefetch queue.
//  2. grid (h, iq, b): wgid % 8 == h -> each XCD runs exactly one h, its
//     1MB bias slice stays L2-resident; the 4 iq blocks of one (b,h) are
//     dispatched adjacently -> K/V re-reads become L2 hits.
//  3. s_setprio(1) around MFMA clusters (T5).
// ---------------------------------------------------------------------------
__global__ __launch_bounds__(256, 4) void attn_k(
    const short* __restrict__ Q, const short* __restrict__ K,
    const short* __restrict__ Vt, const float* __restrict__ biasS,
    const float* __restrict__ maskF, short* __restrict__ G)
{
  __shared__ __align__(16) short Ks[2][64 * 64];   // [j][d], xor-swizzled 8-chunks
  __shared__ __align__(16) short Vs[2][64 * 64];   // [d][j], xor-swizzled
  __shared__ __align__(16) short Pall[4][16 * 64]; // per-wave, reused per i-tile
  const int tid = threadIdx.x;
  const int w = tid >> 6, lane = tid & 63;
  const int m = lane & 15, q = lane >> 4;
  const int m7 = m & 7;
  const int h = blockIdx.x, iq = blockIdx.y, b = blockIdx.z;
  const int i0w = iq * 128 + w * 32;               // this wave's first Q row
  const size_t bh = (size_t)b * 8 + h;
  const short* Qp = Q + (bh * 512 + i0w) * 64;
  const short* Kp = K + bh * 512 * 64;
  const short* Vp = Vt + bh * 64 * 512;
  const float* mkp = maskF + b * 512;
  short* Ps = Pall[w];

  const int srow = lane >> 3;                      // staging row in 8-row group
  const int gchunk = (lane & 7) ^ (srow & 7);      // global 8-short chunk to fetch

  // Q frags (B-operand): lane holds Q[i=m][d=q*8+jj]
  bf16x8 qf[2][2];
#pragma unroll
  for (int it = 0; it < 2; ++it) {
    qf[it][0] = *(const bf16x8*)&Qp[(it * 16 + m) * 64 + q * 8];
    qf[it][1] = *(const bf16x8*)&Qp[(it * 16 + m) * 64 + 32 + q * 8];
  }
  float miF[2];
#pragma unroll
  for (int it = 0; it < 2; ++it) miF[it] = mkp[i0w + it * 16 + m];

  // stage chunk 0
#pragma unroll
  for (int s2 = 0; s2 < 2; ++s2) {
    const int rr = w * 16 + s2 * 8;
    cp16(Kp + (size_t)(rr + srow) * 64 + gchunk * 8, &Ks[0][rr * 64]);
    cp16(Vp + (size_t)(rr + srow) * 512 + gchunk * 8, &Vs[0][rr * 64]);
  }
  f32x4 o[2][4] = {};
  float l[2] = {0.f, 0.f};
  __syncthreads();                                 // chunk 0 staged

  const float SCL = 0.125f * 1.4426950408889634f;  // scale * log2(e)
  const float* bpRow = biasS + ((size_t)h * 512 + i0w) * 512;
  for (int c = 0; c < 8; ++c) {
    const int p = c & 1;

    // 1) mask + bias register loads FIRST (before prefetch -> vmcnt waits on
    //    these do not drain the cp16 queue)
    f32x4 mjf[4];
#pragma unroll
    for (int jt = 0; jt < 4; ++jt)
      mjf[jt] = *(const f32x4*)&mkp[c * 64 + jt * 16 + q * 4];
    f32x4 bv[2][4];
#pragma unroll
    for (int it = 0; it < 2; ++it)
#pragma unroll
      for (int jt = 0; jt < 4; ++jt)
        bv[it][jt] = *(const f32x4*)&bpRow[(it * 16 + m) * 512 + c * 64 + jt * 16 + q * 4];

    // 2) prefetch next chunk
    if (c < 7) {
      const int jn = (c + 1) * 64;
#pragma unroll
      for (int s2 = 0; s2 < 2; ++s2) {
        const int rr = w * 16 + s2 * 8;
        cp16(Kp + (size_t)(jn + rr + srow) * 64 + gchunk * 8, &Ks[p ^ 1][rr * 64]);
        cp16(Vp + (size_t)(rr + srow) * 512 + jn + gchunk * 8, &Vs[p ^ 1][rr * 64]);
      }
    }

    // 3) QK^T (transposed): S^T tile = mfma(A=K rows j, B=Q cols i)
    // lane holds S[i = it*16+m][j = c*64 + jt*16 + q*4 + r]
    f32x4 s[2][4];
    __builtin_amdgcn_s_setprio(1);
#pragma unroll
    for (int jt = 0; jt < 4; ++jt) {
      const bf16x8 ka = *(const bf16x8*)&Ks[p][(jt * 16 + m) * 64 + ((q ^ m7) * 8)];
      const bf16x8 kb = *(const bf16x8*)&Ks[p][(jt * 16 + m) * 64 + (((4 + q) ^ m7) * 8)];
#pragma unroll
      for (int it = 0; it < 2; ++it) {
        f32x4 a = {};
        a = mfma16(ka, qf[it][0], a);
        s[it][jt] = mfma16(kb, qf[it][1], a);
      }
    }
    __builtin_amdgcn_s_setprio(0);

    // 4) softmax + PV per i-tile
#pragma unroll
    for (int it = 0; it < 2; ++it) {
      // softmax terms -> packed b64 P writes (4 consecutive j per lane)
#pragma unroll
      for (int jt = 0; jt < 4; ++jt) {
        s16x4 st;
#pragma unroll
        for (int r = 0; r < 4; ++r) {
          const float v = fmaf(s[it][jt][r], SCL, bv[it][jt][r]);
          float e = exp2f(v) * mjf[jt][r];
          e = (miF[it] != 0.0f) ? e : 1.0f;        // fully-masked row -> uniform
          const unsigned u = __float_as_uint(e);
          st[r] = (short)(u >> 16);                // trunc pack
          l[it] += __uint_as_float(u & 0xffff0000u); // == stored P
        }
        *(s16x4*)&Ps[m * 64 + (((jt * 2 + (q >> 1)) ^ m7) * 8) + (q & 1) * 4] = st;
      }
      // PV for this i-tile: A = P rows i, B = V^T cols d
      const bf16x8 pa = *(const bf16x8*)&Ps[m * 64 + ((q ^ m7) * 8)];
      const bf16x8 pb = *(const bf16x8*)&Ps[m * 64 + (((4 + q) ^ m7) * 8)];
      __builtin_amdgcn_s_setprio(1);
#pragma unroll
      for (int dt = 0; dt < 4; ++dt) {
        const bf16x8 va = *(const bf16x8*)&Vs[p][(dt * 16 + m) * 64 + ((q ^ m7) * 8)];
        const bf16x8 vb = *(const bf16x8*)&Vs[p][(dt * 16 + m) * 64 + (((4 + q) ^ m7) * 8)];
        o[it][dt] = mfma16(pa, va, o[it][dt]);
        o[it][dt] = mfma16(pb, vb, o[it][dt]);
      }
      __builtin_amdgcn_s_setprio(0);
    }
    __syncthreads();  // Ks/Vs[p] reads done; prefetch (p^1) drained
  }

  // ---- epilogue: reduce l over q-lanes (lane holds row i = it*16+m) ----
#pragma unroll
  for (int it = 0; it < 2; ++it) {
    float t = l[it];
    t += __shfl_xor(t, 16, 64);
    t += __shfl_xor(t, 32, 64);
    l[it] = 1.0f / t;
  }
  const int colb = h * 64;
#pragma unroll
  for (int it = 0; it < 2; ++it) {
    // broadcast 1/l to o's row layout (row = q*4+r): pull from lane m = q*4+r
    float lr[4];
#pragma unroll
    for (int r = 0; r < 4; ++r) lr[r] = __shfl(l[it], q * 4 + r, 16);
#pragma unroll
    for (int dt = 0; dt < 4; ++dt)
#pragma unroll
      for (int r = 0; r < 4; ++r) {
        const int row = i0w + it * 16 + q * 4 + r;
        const size_t addr = ((size_t)b * 512 + row) * 512 + colb + dt * 16 + m;
        const float gate = bf2f(G[addr]);
        G[addr] = f2bf(o[it][dt][r] * lr[r] * gate);
      }
  }
}

// ---------------------------------------------------------------------------
// GEMM3: out = OG[32768,512] @ Wo + bo   (B^T = WoT[256][512]); fp32 output.
// Grid (2 n-tiles fastest, 256 m-tiles).
// ---------------------------------------------------------------------------
__global__ __launch_bounds__(256, 2) void gemm_og(
    const short* __restrict__ A, const short* __restrict__ Bt,
    const float* __restrict__ bo, float* __restrict__ out)
{
  __shared__ __align__(16) short As[128 * 32];
  __shared__ __align__(16) short Bs[128 * 32];
  const int tid = threadIdx.x;
  const int w = tid >> 6, lane = tid & 63;
  const int m = lane & 15, q = lane >> 4;
  const int n0 = blockIdx.x * 128, m0 = blockIdx.y * 128;
  const int ric = lane >> 2, cslot = lane & 3;
  const int csw = cslot ^ ((ric >> 1) & 3);
  const int wr = (w >> 1) * 64, wc = (w & 1) * 64;
  const int rsw = (m >> 1) & 3;
  f32x4 acc[4][4] = {};
  for (int k0 = 0; k0 < INNER_; k0 += 32) {
    __syncthreads();
#pragma unroll
    for (int s = 0; s < 2; ++s) {
      const int rr = w * 32 + s * 16;
      cp16(A  + (size_t)(m0 + rr + ric) * INNER_ + (k0 + csw * 8), &As[rr * 32]);
      cp16(Bt + (size_t)(n0 + rr + ric) * INNER_ + (k0 + csw * 8), &Bs[rr * 32]);
    }
    __syncthreads();
    bf16x8 af[4], bfv[4];
#pragma unroll
    for (int t = 0; t < 4; ++t) {
      af[t]  = *(const bf16x8*)&As[(wr + t * 16 + m) * 32 + ((q ^ rsw) * 8)];
      bfv[t] = *(const bf16x8*)&Bs[(wc + t * 16 + m) * 32 + ((q ^ rsw) * 8)];
    }
#pragma unroll
    for (int ti = 0; ti < 4; ++ti)
#pragma unroll
      for (int tj = 0; tj < 4; ++tj)
        acc[ti][tj] = mfma16(af[ti], bfv[tj], acc[ti][tj]);
  }
#pragma unroll
  for (int ti = 0; ti < 4; ++ti) {
    const int row = m0 + wr + ti * 16 + q * 4;
#pragma unroll
    for (int tj = 0; tj < 4; ++tj) {
      const int c = n0 + wc + tj * 16 + m;
      const float bov = bo[c];
#pragma unroll
      for (int r = 0; r < 4; ++r)
        out[(size_t)(row + r) * 256 + c] = acc[ti][tj][r] + bov;
    }
  }
}

// ---------------------------------------------------------------------------
extern "C" void kernel_launch(void* const* d_in, const int* in_sizes, int n_in,
                              void* d_out, int out_size, void* d_ws, size_t ws_size,
                              hipStream_t stream)
{
  (void)in_sizes; (void)n_in; (void)out_size; (void)ws_size;
  const float* x    = (const float*)d_in[0];
  const int*   mask = (const int*)d_in[1];
  const float* bias = (const float*)d_in[2];
  const float* Wq   = (const float*)d_in[3];
  const float* Wkv  = (const float*)d_in[4];
  const float* Wo   = (const float*)d_in[5];
  const float* bo   = (const float*)d_in[6];
  const float* Wg   = (const float*)d_in[7];
  const float* bg   = (const float*)d_in[8];
  float* out = (float*)d_out;

  char* ws = (char*)d_ws;
  size_t off = 0;
  short* Wt1   = (short*)(ws + off); off += (size_t)2048 * 256 * 2;         // 1.0 MiB
  short* WoT   = (short*)(ws + off); off += (size_t)256 * 512 * 2;          // 0.25 MiB
  short* xb    = (short*)(ws + off); off += (size_t)32768 * 256 * 2;        // 16 MiB
  short* Qb    = (short*)(ws + off); off += (size_t)B_ * H_ * N_ * DH_ * 2; // 32 MiB
  short* Kb    = (short*)(ws + off); off += (size_t)B_ * H_ * N_ * DH_ * 2; // 32 MiB
  short* Vt    = (short*)(ws + off); off += (size_t)B_ * H_ * DH_ * N_ * 2; // 32 MiB
  short* G     = (short*)(ws + off); off += (size_t)B_ * N_ * INNER_ * 2;   // 32 MiB
  float* biasS = (float*)(ws + off); off += (size_t)H_ * N_ * N_ * 4;       // 8 MiB
  float* maskF = (float*)(ws + off); off += (size_t)B_ * N_ * 4;            // 128 KiB

  prep_k<<<(PREP_TOT + 255) / 256, 256, 0, stream>>>(x, Wq, Wkv, Wg, Wo, bias, mask,
                                                     Wt1, WoT, xb, biasS, maskF);
  gemm_qkvg<<<dim3(16, 256), 256, 0, stream>>>(xb, Wt1, bg, Qb, Kb, Vt, G);
  attn_k<<<dim3(8, 4, 64), 256, 0, stream>>>(Qb, Kb, Vt, biasS, maskF, G);
  gemm_og<<<dim3(2, 256), 256, 0, stream>>>(G, WoT, bo, out);
}

// Round 3
// 368.698 us; speedup vs baseline: 1.9151x; 1.2818x over previous
//
#include <hip/hip_runtime.h>
#include <stdint.h>

// Problem constants
#define B_    64
#define N_    512
#define DIM_  256
#define H_    8
#define DH_   64
#define INNER_ 512

typedef __attribute__((ext_vector_type(8))) short bf16x8;
typedef __attribute__((ext_vector_type(4))) float f32x4;
typedef __attribute__((ext_vector_type(4))) short s16x4;

typedef const __attribute__((address_space(1))) void* gas_ptr;
typedef __attribute__((address_space(3))) void* las_ptr;

__device__ __forceinline__ short f2bf(float f) {
  unsigned int u = __float_as_uint(f);
  u += 0x7fffu + ((u >> 16) & 1u);          // RNE
  return (short)(u >> 16);
}
__device__ __forceinline__ float bf2f(short s) {
  return __uint_as_float(((unsigned int)(unsigned short)s) << 16);
}
__device__ __forceinline__ void cp16(const void* g, void* l) {
  __builtin_amdgcn_global_load_lds((gas_ptr)g, (las_ptr)l, 16, 0, 0);
}
__device__ __forceinline__ f32x4 mfma16(bf16x8 a, bf16x8 b, f32x4 c) {
  return __builtin_amdgcn_mfma_f32_16x16x32_bf16(a, b, c, 0, 0, 0);
}

// ---------------------------------------------------------------------------
// Prep: fp32 -> bf16 edge conversions (+ scaled bias copy, float mask).
// ---------------------------------------------------------------------------
#define PREP_WT1  (2048 * 256)
#define PREP_WOT  (256 * 512)
#define PREP_X    (32768 * 256)
#define PREP_BIAS (8 * 512 * 512)
#define PREP_MASK (64 * 512)
#define PREP_TOT  (PREP_WT1 + PREP_WOT + PREP_X + PREP_BIAS + PREP_MASK)

__global__ void prep_k(const float* __restrict__ x,
                       const float* __restrict__ Wq, const float* __restrict__ Wkv,
                       const float* __restrict__ Wg, const float* __restrict__ Wo,
                       const float* __restrict__ bias, const int* __restrict__ mask,
                       short* __restrict__ Wt1, short* __restrict__ WoT,
                       short* __restrict__ xb, float* __restrict__ biasS,
                       float* __restrict__ maskF)
{
  const int idx = blockIdx.x * 256 + threadIdx.x;
  if (idx < PREP_WT1) {
    const int n = idx >> 8, k = idx & 255;
    float v;
    if (n < 512)        v = Wq[k * 512 + n];
    else if (n < 1536)  v = Wkv[k * 1024 + (n - 512)];   // K cols then V cols
    else                v = Wg[k * 512 + (n - 1536)];
    Wt1[idx] = f2bf(v);
  } else if (idx < PREP_WT1 + PREP_WOT) {
    const int j = idx - PREP_WT1;
    const int n = j >> 9, k = j & 511;
    WoT[j] = f2bf(Wo[k * 256 + n]);
  } else if (idx < PREP_WT1 + PREP_WOT + PREP_X) {
    const int j = idx - (PREP_WT1 + PREP_WOT);
    xb[j] = f2bf(x[j]);
  } else if (idx < PREP_WT1 + PREP_WOT + PREP_X + PREP_BIAS) {
    const int j = idx - (PREP_WT1 + PREP_WOT + PREP_X);
    biasS[j] = bias[j] * 1.4426950408889634f;            // coalesced scaled copy
  } else if (idx < PREP_TOT) {
    const int j = idx - (PREP_WT1 + PREP_WOT + PREP_X + PREP_BIAS);
    maskF[j] = mask[j] ? 1.0f : 0.0f;
  }
}

// ---------------------------------------------------------------------------
// GEMM1: C = xb[32768,256] @ Wt1^T  (N=2048 fused Q|K|V|G), all bf16.
// NEW: for Q/K/G regions the MFMA operands are SWAPPED (C comes out
// transposed: each lane holds 4 consecutive n-columns for one x-row) so all
// stores become s16x4 (8B) instead of scalar 2B. V region keeps the original
// orientation (its [d][n] transposed store is vector-friendly as-is).
// ---------------------------------------------------------------------------
__global__ __launch_bounds__(256, 2) void gemm_qkvg(
    const short* __restrict__ X, const short* __restrict__ Wt,
    const float* __restrict__ bg,
    short* __restrict__ Q, short* __restrict__ Kb,
    short* __restrict__ Vt, short* __restrict__ G)
{
  __shared__ __align__(16) short As[128 * 32];
  __shared__ __align__(16) short Bs[128 * 32];
  const int tid = threadIdx.x;
  const int w = tid >> 6, lane = tid & 63;
  const int m = lane & 15, q = lane >> 4;
  const int n0 = blockIdx.x * 128, m0 = blockIdx.y * 128;
  const int region = blockIdx.x >> 2;           // 0=Q 1=K 2=V 3=G
  const bool vreg = (region == 2);
  const int ric = lane >> 2, cslot = lane & 3;
  const int csw = cslot ^ ((ric >> 1) & 3);
  const int wr = (w >> 1) * 64, wc = (w & 1) * 64;
  const int rsw = (m >> 1) & 3;
  f32x4 acc[4][4] = {};
  for (int k0 = 0; k0 < DIM_; k0 += 32) {
    __syncthreads();
#pragma unroll
    for (int s = 0; s < 2; ++s) {
      const int rr = w * 32 + s * 16;
      cp16(X  + (size_t)(m0 + rr + ric) * DIM_ + (k0 + csw * 8), &As[rr * 32]);
      cp16(Wt + (size_t)(n0 + rr + ric) * DIM_ + (k0 + csw * 8), &Bs[rr * 32]);
    }
    __syncthreads();
    bf16x8 af[4], bfv[4];
#pragma unroll
    for (int t = 0; t < 4; ++t) {
      af[t]  = *(const bf16x8*)&As[(wr + t * 16 + m) * 32 + ((q ^ rsw) * 8)];
      bfv[t] = *(const bf16x8*)&Bs[(wc + t * 16 + m) * 32 + ((q ^ rsw) * 8)];
    }
    if (vreg) {
#pragma unroll
      for (int ti = 0; ti < 4; ++ti)
#pragma unroll
        for (int tj = 0; tj < 4; ++tj)
          acc[ti][tj] = mfma16(af[ti], bfv[tj], acc[ti][tj]);
    } else {
#pragma unroll
      for (int ti = 0; ti < 4; ++ti)
#pragma unroll
        for (int tj = 0; tj < 4; ++tj)
          acc[ti][tj] = mfma16(bfv[tj], af[ti], acc[ti][tj]);  // transposed C
    }
  }
  if (vreg) {                                    // V -> transposed [B,H,DH,N]
    const int cb = (n0 & 511) + wc;
#pragma unroll
    for (int ti = 0; ti < 4; ++ti) {
      const int mgb = m0 + wr + ti * 16 + q * 4;
      const int b = mgb >> 9, n = mgb & 511;
#pragma unroll
      for (int tj = 0; tj < 4; ++tj) {
        const int c = cb + tj * 16 + m;
        const int h = c >> 6, d = c & 63;
        s16x4 st;
#pragma unroll
        for (int r = 0; r < 4; ++r) st[r] = f2bf(acc[ti][tj][r]);
        *(s16x4*)&Vt[((size_t)(b * 8 + h) * 64 + d) * 512 + n] = st;
      }
    }
  } else {                                       // Q / K / G: transposed C
#pragma unroll
    for (int ti = 0; ti < 4; ++ti) {
      const int xrow = m0 + wr + ti * 16 + m;    // one x-row per lane
      const int b = xrow >> 9, n = xrow & 511;
#pragma unroll
      for (int tj = 0; tj < 4; ++tj) {
        const int cvec = (n0 & 511) + wc + tj * 16 + q * 4;  // 4 consecutive cols
        if (region == 3) {                       // gates = x@Wg + bg
          const f32x4 bg4 = *(const f32x4*)&bg[cvec];
          s16x4 st;
#pragma unroll
          for (int r = 0; r < 4; ++r) st[r] = f2bf(acc[ti][tj][r] + bg4[r]);
          *(s16x4*)&G[(size_t)xrow * 512 + cvec] = st;
        } else {
          const int h = cvec >> 6, d0 = cvec & 63;
          s16x4 st;
#pragma unroll
          for (int r = 0; r < 4; ++r) st[r] = f2bf(acc[ti][tj][r]);
          short* dst = (region == 0) ? Q : Kb;
          *(s16x4*)&dst[((size_t)(b * 8 + h) * 512 + n) * 64 + d0] = st;
        }
      }
    }
  }
}

// ---------------------------------------------------------------------------
// Attention, flash-style with TRANSPOSED score MFMA (S^T = K·Q^T).
// Round-0 body (verified 157us) + zero-register-cost deltas only:
//  - grid (h, iq, b): wgid % 8 == h -> each XCD pinned to one h (1MB bias
//    slice L2-resident); 4 iq blocks of one (b,h) dispatched adjacently.
//  - s_setprio(1) around MFMA clusters (T5, attn-proven +4-7%).
// ---------------------------------------------------------------------------
__global__ __launch_bounds__(256, 4) void attn_k(
    const short* __restrict__ Q, const short* __restrict__ K,
    const short* __restrict__ Vt, const float* __restrict__ biasS,
    const float* __restrict__ maskF, short* __restrict__ G)
{
  __shared__ __align__(16) short Ks[2][64 * 64];   // [j][d], xor-swizzled 8-chunks
  __shared__ __align__(16) short Vs[2][64 * 64];   // [d][j], xor-swizzled
  __shared__ __align__(16) short Pall[4][16 * 64]; // per-wave, reused per i-tile
  const int tid = threadIdx.x;
  const int w = tid >> 6, lane = tid & 63;
  const int m = lane & 15, q = lane >> 4;
  const int m7 = m & 7;
  const int h = blockIdx.x, iq = blockIdx.y, b = blockIdx.z;
  const int i0w = iq * 128 + w * 32;               // this wave's first Q row
  const size_t bh = (size_t)b * 8 + h;
  const short* Qp = Q + (bh * 512 + i0w) * 64;
  const short* Kp = K + bh * 512 * 64;
  const short* Vp = Vt + bh * 64 * 512;
  const float* mkp = maskF + b * 512;
  short* Ps = Pall[w];

  const int srow = lane >> 3;                      // staging row in 8-row group
  const int gchunk = (lane & 7) ^ (srow & 7);      // global 8-short chunk to fetch

  // Q frags (B-operand): lane holds Q[i=m][d=q*8+jj]
  bf16x8 qf[2][2];
#pragma unroll
  for (int it = 0; it < 2; ++it) {
    qf[it][0] = *(const bf16x8*)&Qp[(it * 16 + m) * 64 + q * 8];
    qf[it][1] = *(const bf16x8*)&Qp[(it * 16 + m) * 64 + 32 + q * 8];
  }
  float miF[2];
#pragma unroll
  for (int it = 0; it < 2; ++it) miF[it] = mkp[i0w + it * 16 + m];

  // stage chunk 0
#pragma unroll
  for (int s2 = 0; s2 < 2; ++s2) {
    const int rr = w * 16 + s2 * 8;
    cp16(Kp + (size_t)(rr + srow) * 64 + gchunk * 8, &Ks[0][rr * 64]);
    cp16(Vp + (size_t)(rr + srow) * 512 + gchunk * 8, &Vs[0][rr * 64]);
  }
  f32x4 o[2][4] = {};
  float l[2] = {0.f, 0.f};
  __syncthreads();                                 // chunk 0 staged

  const float SCL = 0.125f * 1.4426950408889634f;  // scale * log2(e)
  for (int c = 0; c < 8; ++c) {
    const int p = c & 1;
    if (c < 7) {                                   // prefetch next chunk
      const int jn = (c + 1) * 64;
#pragma unroll
      for (int s2 = 0; s2 < 2; ++s2) {
        const int rr = w * 16 + s2 * 8;
        cp16(Kp + (size_t)(jn + rr + srow) * 64 + gchunk * 8, &Ks[p ^ 1][rr * 64]);
        cp16(Vp + (size_t)(rr + srow) * 512 + jn + gchunk * 8, &Vs[p ^ 1][rr * 64]);
      }
    }
    // mask (f32x4 per jt): j = c*64 + jt*16 + q*4 + r
    f32x4 mjf[4];
#pragma unroll
    for (int jt = 0; jt < 4; ++jt)
      mjf[jt] = *(const f32x4*)&mkp[c * 64 + jt * 16 + q * 4];

    // QK^T (transposed): S^T tile = mfma(A=K rows j, B=Q cols i)
    // lane holds S[i = it*16+m][j = c*64 + jt*16 + q*4 + r]
    f32x4 s[2][4];
    __builtin_amdgcn_s_setprio(1);
#pragma unroll
    for (int jt = 0; jt < 4; ++jt) {
      const bf16x8 ka = *(const bf16x8*)&Ks[p][(jt * 16 + m) * 64 + ((q ^ m7) * 8)];
      const bf16x8 kb = *(const bf16x8*)&Ks[p][(jt * 16 + m) * 64 + (((4 + q) ^ m7) * 8)];
#pragma unroll
      for (int it = 0; it < 2; ++it) {
        f32x4 a = {};
        a = mfma16(ka, qf[it][0], a);
        s[it][jt] = mfma16(kb, qf[it][1], a);
      }
    }
    __builtin_amdgcn_s_setprio(0);
#pragma unroll
    for (int it = 0; it < 2; ++it) {
      // bias (fp32, prescaled by log2e, original [h][i][j] layout)
      const float* bp = biasS + ((size_t)h * 512 + i0w + it * 16 + m) * 512 + c * 64;
      f32x4 bv[4];
#pragma unroll
      for (int jt = 0; jt < 4; ++jt)
        bv[jt] = *(const f32x4*)&bp[jt * 16 + q * 4];
      // softmax terms -> packed b64 P writes (4 consecutive j per lane)
#pragma unroll
      for (int jt = 0; jt < 4; ++jt) {
        s16x4 st;
#pragma unroll
        for (int r = 0; r < 4; ++r) {
          const float v = fmaf(s[it][jt][r], SCL, bv[jt][r]);
          float e = exp2f(v) * mjf[jt][r];
          e = (miF[it] != 0.0f) ? e : 1.0f;        // fully-masked row -> uniform
          const unsigned u = __float_as_uint(e);
          st[r] = (short)(u >> 16);                // trunc pack
          l[it] += __uint_as_float(u & 0xffff0000u); // == stored P
        }
        *(s16x4*)&Ps[m * 64 + (((jt * 2 + (q >> 1)) ^ m7) * 8) + (q & 1) * 4] = st;
      }
      // PV for this i-tile: A = P rows i, B = V^T cols d
      const bf16x8 pa = *(const bf16x8*)&Ps[m * 64 + ((q ^ m7) * 8)];
      const bf16x8 pb = *(const bf16x8*)&Ps[m * 64 + (((4 + q) ^ m7) * 8)];
      __builtin_amdgcn_s_setprio(1);
#pragma unroll
      for (int dt = 0; dt < 4; ++dt) {
        const bf16x8 va = *(const bf16x8*)&Vs[p][(dt * 16 + m) * 64 + ((q ^ m7) * 8)];
        const bf16x8 vb = *(const bf16x8*)&Vs[p][(dt * 16 + m) * 64 + (((4 + q) ^ m7) * 8)];
        o[it][dt] = mfma16(pa, va, o[it][dt]);
        o[it][dt] = mfma16(pb, vb, o[it][dt]);
      }
      __builtin_amdgcn_s_setprio(0);
    }
    __syncthreads();  // Ks/Vs[p] reads done; prefetch (p^1) drained
  }

  // ---- epilogue: reduce l over q-lanes (lane holds row i = it*16+m) ----
#pragma unroll
  for (int it = 0; it < 2; ++it) {
    float t = l[it];
    t += __shfl_xor(t, 16, 64);
    t += __shfl_xor(t, 32, 64);
    l[it] = 1.0f / t;
  }
  const int colb = h * 64;
#pragma unroll
  for (int it = 0; it < 2; ++it) {
    // broadcast 1/l to o's row layout (row = q*4+r): pull from lane m = q*4+r
    float lr[4];
#pragma unroll
    for (int r = 0; r < 4; ++r) lr[r] = __shfl(l[it], q * 4 + r, 16);
#pragma unroll
    for (int dt = 0; dt < 4; ++dt)
#pragma unroll
      for (int r = 0; r < 4; ++r) {
        const int row = i0w + it * 16 + q * 4 + r;
        const size_t addr = ((size_t)b * 512 + row) * 512 + colb + dt * 16 + m;
        const float gate = bf2f(G[addr]);
        G[addr] = f2bf(o[it][dt][r] * lr[r] * gate);
      }
  }
}

// ---------------------------------------------------------------------------
// GEMM3: out = OG[32768,512] @ Wo + bo   (B^T = WoT[256][512]); fp32 output.
// NEW: swapped MFMA operands -> each lane holds 4 consecutive out-columns for
// one row -> f32x4 (16B) stores replace 64 scalar dword stores.
// ---------------------------------------------------------------------------
__global__ __launch_bounds__(256, 2) void gemm_og(
    const short* __restrict__ A, const short* __restrict__ Bt,
    const float* __restrict__ bo, float* __restrict__ out)
{
  __shared__ __align__(16) short As[128 * 32];
  __shared__ __align__(16) short Bs[128 * 32];
  const int tid = threadIdx.x;
  const int w = tid >> 6, lane = tid & 63;
  const int m = lane & 15, q = lane >> 4;
  const int n0 = blockIdx.x * 128, m0 = blockIdx.y * 128;
  const int ric = lane >> 2, cslot = lane & 3;
  const int csw = cslot ^ ((ric >> 1) & 3);
  const int wr = (w >> 1) * 64, wc = (w & 1) * 64;
  const int rsw = (m >> 1) & 3;
  f32x4 acc[4][4] = {};
  for (int k0 = 0; k0 < INNER_; k0 += 32) {
    __syncthreads();
#pragma unroll
    for (int s = 0; s < 2; ++s) {
      const int rr = w * 32 + s * 16;
      cp16(A  + (size_t)(m0 + rr + ric) * INNER_ + (k0 + csw * 8), &As[rr * 32]);
      cp16(Bt + (size_t)(n0 + rr + ric) * INNER_ + (k0 + csw * 8), &Bs[rr * 32]);
    }
    __syncthreads();
    bf16x8 af[4], bfv[4];
#pragma unroll
    for (int t = 0; t < 4; ++t) {
      af[t]  = *(const bf16x8*)&As[(wr + t * 16 + m) * 32 + ((q ^ rsw) * 8)];
      bfv[t] = *(const bf16x8*)&Bs[(wc + t * 16 + m) * 32 + ((q ^ rsw) * 8)];
    }
#pragma unroll
    for (int ti = 0; ti < 4; ++ti)
#pragma unroll
      for (int tj = 0; tj < 4; ++tj)
        acc[ti][tj] = mfma16(bfv[tj], af[ti], acc[ti][tj]);   // transposed C
  }
#pragma unroll
  for (int ti = 0; ti < 4; ++ti) {
    const int row = m0 + wr + ti * 16 + m;       // one output row per lane
#pragma unroll
    for (int tj = 0; tj < 4; ++tj) {
      const int c0 = n0 + wc + tj * 16 + q * 4;  // 4 consecutive out-columns
      const f32x4 bo4 = *(const f32x4*)&bo[c0];
      f32x4 v;
#pragma unroll
      for (int r = 0; r < 4; ++r) v[r] = acc[ti][tj][r] + bo4[r];
      *(f32x4*)&out[(size_t)row * 256 + c0] = v;
    }
  }
}

// ---------------------------------------------------------------------------
extern "C" void kernel_launch(void* const* d_in, const int* in_sizes, int n_in,
                              void* d_out, int out_size, void* d_ws, size_t ws_size,
                              hipStream_t stream)
{
  (void)in_sizes; (void)n_in; (void)out_size; (void)ws_size;
  const float* x    = (const float*)d_in[0];
  const int*   mask = (const int*)d_in[1];
  const float* bias = (const float*)d_in[2];
  const float* Wq   = (const float*)d_in[3];
  const float* Wkv  = (const float*)d_in[4];
  const float* Wo   = (const float*)d_in[5];
  const float* bo   = (const float*)d_in[6];
  const float* Wg   = (const float*)d_in[7];
  const float* bg   = (const float*)d_in[8];
  float* out = (float*)d_out;

  char* ws = (char*)d_ws;
  size_t off = 0;
  short* Wt1   = (short*)(ws + off); off += (size_t)2048 * 256 * 2;         // 1.0 MiB
  short* WoT   = (short*)(ws + off); off += (size_t)256 * 512 * 2;          // 0.25 MiB
  short* xb    = (short*)(ws + off); off += (size_t)32768 * 256 * 2;        // 16 MiB
  short* Qb    = (short*)(ws + off); off += (size_t)B_ * H_ * N_ * DH_ * 2; // 32 MiB
  short* Kb    = (short*)(ws + off); off += (size_t)B_ * H_ * N_ * DH_ * 2; // 32 MiB
  short* Vt    = (short*)(ws + off); off += (size_t)B_ * H_ * DH_ * N_ * 2; // 32 MiB
  short* G     = (short*)(ws + off); off += (size_t)B_ * N_ * INNER_ * 2;   // 32 MiB
  float* biasS = (float*)(ws + off); off += (size_t)H_ * N_ * N_ * 4;       // 8 MiB
  float* maskF = (float*)(ws + off); off += (size_t)B_ * N_ * 4;            // 128 KiB

  prep_k<<<(PREP_TOT + 255) / 256, 256, 0, stream>>>(x, Wq, Wkv, Wg, Wo, bias, mask,
                                                     Wt1, WoT, xb, biasS, maskF);
  gemm_qkvg<<<dim3(16, 256), 256, 0, stream>>>(xb, Wt1, bg, Qb, Kb, Vt, G);
  attn_k<<<dim3(8, 4, 64), 256, 0, stream>>>(Qb, Kb, Vt, biasS, maskF, G);
  gemm_og<<<dim3(2, 256), 256, 0, stream>>>(G, WoT, bo, out);
}

// Round 4
// 309.067 us; speedup vs baseline: 2.2846x; 1.1929x over previous
//
#include <hip/hip_runtime.h>
#include <stdint.h>

// Problem constants
#define B_    64
#define N_    512
#define DIM_  256
#define H_    8
#define DH_   64
#define INNER_ 512

typedef __attribute__((ext_vector_type(8))) short bf16x8;
typedef __attribute__((ext_vector_type(4))) float f32x4;
typedef __attribute__((ext_vector_type(4))) short s16x4;

typedef const __attribute__((address_space(1))) void* gas_ptr;
typedef __attribute__((address_space(3))) void* las_ptr;

__device__ __forceinline__ short f2bf(float f) {
  unsigned int u = __float_as_uint(f);
  u += 0x7fffu + ((u >> 16) & 1u);          // RNE
  return (short)(u >> 16);
}
__device__ __forceinline__ float bf2f(short s) {
  return __uint_as_float(((unsigned int)(unsigned short)s) << 16);
}
__device__ __forceinline__ void cp16(const void* g, void* l) {
  __builtin_amdgcn_global_load_lds((gas_ptr)g, (las_ptr)l, 16, 0, 0);
}
__device__ __forceinline__ f32x4 mfma16(bf16x8 a, bf16x8 b, f32x4 c) {
  return __builtin_amdgcn_mfma_f32_16x16x32_bf16(a, b, c, 0, 0, 0);
}

// ---------------------------------------------------------------------------
// Prep: fp32 -> bf16 edge conversions (+ scaled bias copy, float mask).
// ---------------------------------------------------------------------------
#define PREP_WT1  (2048 * 256)
#define PREP_WOT  (256 * 512)
#define PREP_X    (32768 * 256)
#define PREP_BIAS (8 * 512 * 512)
#define PREP_MASK (64 * 512)
#define PREP_TOT  (PREP_WT1 + PREP_WOT + PREP_X + PREP_BIAS + PREP_MASK)

__global__ void prep_k(const float* __restrict__ x,
                       const float* __restrict__ Wq, const float* __restrict__ Wkv,
                       const float* __restrict__ Wg, const float* __restrict__ Wo,
                       const float* __restrict__ bias, const int* __restrict__ mask,
                       short* __restrict__ Wt1, short* __restrict__ WoT,
                       short* __restrict__ xb, float* __restrict__ biasS,
                       float* __restrict__ maskF)
{
  const int idx = blockIdx.x * 256 + threadIdx.x;
  if (idx < PREP_WT1) {
    const int n = idx >> 8, k = idx & 255;
    float v;
    if (n < 512)        v = Wq[k * 512 + n];
    else if (n < 1536)  v = Wkv[k * 1024 + (n - 512)];   // K cols then V cols
    else                v = Wg[k * 512 + (n - 1536)];
    Wt1[idx] = f2bf(v);
  } else if (idx < PREP_WT1 + PREP_WOT) {
    const int j = idx - PREP_WT1;
    const int n = j >> 9, k = j & 511;
    WoT[j] = f2bf(Wo[k * 256 + n]);
  } else if (idx < PREP_WT1 + PREP_WOT + PREP_X) {
    const int j = idx - (PREP_WT1 + PREP_WOT);
    xb[j] = f2bf(x[j]);
  } else if (idx < PREP_WT1 + PREP_WOT + PREP_X + PREP_BIAS) {
    const int j = idx - (PREP_WT1 + PREP_WOT + PREP_X);
    biasS[j] = bias[j] * 1.4426950408889634f;            // coalesced scaled copy
  } else if (idx < PREP_TOT) {
    const int j = idx - (PREP_WT1 + PREP_WOT + PREP_X + PREP_BIAS);
    maskF[j] = mask[j] ? 1.0f : 0.0f;
  }
}

// ---------------------------------------------------------------------------
// GEMM1: C = xb[32768,256] @ Wt1^T  (N=2048 fused Q|K|V|G), all bf16.
// Q/K/G regions use SWAPPED MFMA operands (transposed C: lane holds 4
// consecutive n-columns of one x-row) -> s16x4 stores. V keeps original
// orientation for its [d][n] transposed store.
// ---------------------------------------------------------------------------
__global__ __launch_bounds__(256, 2) void gemm_qkvg(
    const short* __restrict__ X, const short* __restrict__ Wt,
    const float* __restrict__ bg,
    short* __restrict__ Q, short* __restrict__ Kb,
    short* __restrict__ Vt, short* __restrict__ G)
{
  __shared__ __align__(16) short As[128 * 32];
  __shared__ __align__(16) short Bs[128 * 32];
  const int tid = threadIdx.x;
  const int w = tid >> 6, lane = tid & 63;
  const int m = lane & 15, q = lane >> 4;
  const int n0 = blockIdx.x * 128, m0 = blockIdx.y * 128;
  const int region = blockIdx.x >> 2;           // 0=Q 1=K 2=V 3=G
  const bool vreg = (region == 2);
  const int ric = lane >> 2, cslot = lane & 3;
  const int csw = cslot ^ ((ric >> 1) & 3);
  const int wr = (w >> 1) * 64, wc = (w & 1) * 64;
  const int rsw = (m >> 1) & 3;
  f32x4 acc[4][4] = {};
  for (int k0 = 0; k0 < DIM_; k0 += 32) {
    __syncthreads();
#pragma unroll
    for (int s = 0; s < 2; ++s) {
      const int rr = w * 32 + s * 16;
      cp16(X  + (size_t)(m0 + rr + ric) * DIM_ + (k0 + csw * 8), &As[rr * 32]);
      cp16(Wt + (size_t)(n0 + rr + ric) * DIM_ + (k0 + csw * 8), &Bs[rr * 32]);
    }
    __syncthreads();
    bf16x8 af[4], bfv[4];
#pragma unroll
    for (int t = 0; t < 4; ++t) {
      af[t]  = *(const bf16x8*)&As[(wr + t * 16 + m) * 32 + ((q ^ rsw) * 8)];
      bfv[t] = *(const bf16x8*)&Bs[(wc + t * 16 + m) * 32 + ((q ^ rsw) * 8)];
    }
    if (vreg) {
#pragma unroll
      for (int ti = 0; ti < 4; ++ti)
#pragma unroll
        for (int tj = 0; tj < 4; ++tj)
          acc[ti][tj] = mfma16(af[ti], bfv[tj], acc[ti][tj]);
    } else {
#pragma unroll
      for (int ti = 0; ti < 4; ++ti)
#pragma unroll
        for (int tj = 0; tj < 4; ++tj)
          acc[ti][tj] = mfma16(bfv[tj], af[ti], acc[ti][tj]);  // transposed C
    }
  }
  if (vreg) {                                    // V -> transposed [B,H,DH,N]
    const int cb = (n0 & 511) + wc;
#pragma unroll
    for (int ti = 0; ti < 4; ++ti) {
      const int mgb = m0 + wr + ti * 16 + q * 4;
      const int b = mgb >> 9, n = mgb & 511;
#pragma unroll
      for (int tj = 0; tj < 4; ++tj) {
        const int c = cb + tj * 16 + m;
        const int h = c >> 6, d = c & 63;
        s16x4 st;
#pragma unroll
        for (int r = 0; r < 4; ++r) st[r] = f2bf(acc[ti][tj][r]);
        *(s16x4*)&Vt[((size_t)(b * 8 + h) * 64 + d) * 512 + n] = st;
      }
    }
  } else {                                       // Q / K / G: transposed C
#pragma unroll
    for (int ti = 0; ti < 4; ++ti) {
      const int xrow = m0 + wr + ti * 16 + m;    // one x-row per lane
      const int b = xrow >> 9, n = xrow & 511;
#pragma unroll
      for (int tj = 0; tj < 4; ++tj) {
        const int cvec = (n0 & 511) + wc + tj * 16 + q * 4;  // 4 consecutive cols
        if (region == 3) {                       // gates = x@Wg + bg
          const f32x4 bg4 = *(const f32x4*)&bg[cvec];
          s16x4 st;
#pragma unroll
          for (int r = 0; r < 4; ++r) st[r] = f2bf(acc[ti][tj][r] + bg4[r]);
          *(s16x4*)&G[(size_t)xrow * 512 + cvec] = st;
        } else {
          const int h = cvec >> 6, d0 = cvec & 63;
          s16x4 st;
#pragma unroll
          for (int r = 0; r < 4; ++r) st[r] = f2bf(acc[ti][tj][r]);
          short* dst = (region == 0) ? Q : Kb;
          *(s16x4*)&dst[((size_t)(b * 8 + h) * 512 + n) * 64 + d0] = st;
        }
      }
    }
  }
}

// ---------------------------------------------------------------------------
// Attention, flash-style, TRANSPOSED score MFMA (S^T = K·Q^T).
// NEW: KVBLK 64 -> 32. LDS = Ks 2x4K + Vs 2x4K + P 4x1K = 20KB ->
// 8 blocks/CU (32 waves, was 4 blocks) AND halved softmax transients
// (s[2][2], bv[2], mjf[2]) to kill the latent spill (baseline WRITE_SIZE
// 210MB vs 35MB ideal = scratch). 16 chunks of 32 j; same MFMA count.
// 64-B rows (V, P) use slot-xor by (row&3); K rows stay 128B with m7 xor.
// ---------------------------------------------------------------------------
__global__ __launch_bounds__(256, 4) void attn_k(
    const short* __restrict__ Q, const short* __restrict__ K,
    const short* __restrict__ Vt, const float* __restrict__ biasS,
    const float* __restrict__ maskF, short* __restrict__ G)
{
  __shared__ __align__(16) short Ks[2][32 * 64];   // [j][d], xor-swizzled by j&7
  __shared__ __align__(16) short Vs[2][64 * 32];   // [d][j], slot-xor by d&3
  __shared__ __align__(16) short Pall[4][16 * 32]; // per-wave, slot-xor by i&3
  const int tid = threadIdx.x;
  const int w = tid >> 6, lane = tid & 63;
  const int m = lane & 15, q = lane >> 4;
  const int m7 = m & 7, m3 = m & 3;
  const int h = blockIdx.x, iq = blockIdx.y, b = blockIdx.z;
  const int i0w = iq * 128 + w * 32;               // this wave's first Q row
  const size_t bh = (size_t)b * 8 + h;
  const short* Qp = Q + (bh * 512 + i0w) * 64;
  const short* Kp = K + bh * 512 * 64;
  const short* Vp = Vt + bh * 64 * 512;
  const float* mkp = maskF + b * 512;
  short* Ps = Pall[w];

  // K staging: wave w stages rows w*8..w*8+7 (128B rows, 8 chunks of 8 shorts)
  const int srow = lane >> 3;                      // 0..7
  const int gchunk = (lane & 7) ^ srow;            // global d-chunk (xor by row&7)
  // V staging: wave w stages rows w*16..w*16+15 (64B rows, 4 chunks of 8)
  const int vrow = lane >> 2;                      // 0..15
  const int gchunkV = (lane & 3) ^ (vrow & 3);     // global j-chunk (xor by row&3)

  // Q frags (B-operand): lane holds Q[i=m][d=q*8+jj]
  bf16x8 qf[2][2];
#pragma unroll
  for (int it = 0; it < 2; ++it) {
    qf[it][0] = *(const bf16x8*)&Qp[(it * 16 + m) * 64 + q * 8];
    qf[it][1] = *(const bf16x8*)&Qp[(it * 16 + m) * 64 + 32 + q * 8];
  }
  float miF[2];
#pragma unroll
  for (int it = 0; it < 2; ++it) miF[it] = mkp[i0w + it * 16 + m];

  // stage chunk 0 (1 cp16 for K + 1 for V per wave)
  cp16(Kp + (size_t)(w * 8 + srow) * 64 + gchunk * 8, &Ks[0][w * 8 * 64]);
  cp16(Vp + (size_t)(w * 16 + vrow) * 512 + gchunkV * 8, &Vs[0][w * 16 * 32]);

  f32x4 o[2][4] = {};
  float l[2] = {0.f, 0.f};
  __syncthreads();                                 // chunk 0 staged

  const float SCL = 0.125f * 1.4426950408889634f;  // scale * log2(e)
  for (int c = 0; c < 16; ++c) {
    const int p = c & 1;
    if (c < 15) {                                  // prefetch next chunk
      const int jn = (c + 1) * 32;
      cp16(Kp + (size_t)(jn + w * 8 + srow) * 64 + gchunk * 8, &Ks[p ^ 1][w * 8 * 64]);
      cp16(Vp + (size_t)(w * 16 + vrow) * 512 + jn + gchunkV * 8, &Vs[p ^ 1][w * 16 * 32]);
    }
    // mask (f32x4 per jt): j = c*32 + jt*16 + q*4 + r
    f32x4 mjf[2];
#pragma unroll
    for (int jt = 0; jt < 2; ++jt)
      mjf[jt] = *(const f32x4*)&mkp[c * 32 + jt * 16 + q * 4];

    // QK^T (transposed): lane holds S[i = it*16+m][j = c*32 + jt*16 + q*4 + r]
    f32x4 s[2][2];
    __builtin_amdgcn_s_setprio(1);
#pragma unroll
    for (int jt = 0; jt < 2; ++jt) {
      const bf16x8 ka = *(const bf16x8*)&Ks[p][(jt * 16 + m) * 64 + ((q ^ m7) * 8)];
      const bf16x8 kb = *(const bf16x8*)&Ks[p][(jt * 16 + m) * 64 + (((4 + q) ^ m7) * 8)];
#pragma unroll
      for (int it = 0; it < 2; ++it) {
        f32x4 a = {};
        a = mfma16(ka, qf[it][0], a);
        s[it][jt] = mfma16(kb, qf[it][1], a);
      }
    }
    __builtin_amdgcn_s_setprio(0);
#pragma unroll
    for (int it = 0; it < 2; ++it) {
      // bias (fp32, prescaled by log2e, original [h][i][j] layout)
      const float* bp = biasS + ((size_t)h * 512 + i0w + it * 16 + m) * 512 + c * 32;
      f32x4 bv[2];
#pragma unroll
      for (int jt = 0; jt < 2; ++jt)
        bv[jt] = *(const f32x4*)&bp[jt * 16 + q * 4];
      // softmax terms -> packed b64 P writes (4 consecutive j per lane)
#pragma unroll
      for (int jt = 0; jt < 2; ++jt) {
        s16x4 st;
#pragma unroll
        for (int r = 0; r < 4; ++r) {
          const float v = fmaf(s[it][jt][r], SCL, bv[jt][r]);
          float e = exp2f(v) * mjf[jt][r];
          e = (miF[it] != 0.0f) ? e : 1.0f;        // fully-masked row -> uniform
          const unsigned u = __float_as_uint(e);
          st[r] = (short)(u >> 16);                // trunc pack
          l[it] += __uint_as_float(u & 0xffff0000u); // == stored P
        }
        *(s16x4*)&Ps[m * 32 + (((jt * 2 + (q >> 1)) ^ m3) * 8) + (q & 1) * 4] = st;
      }
      // PV for this i-tile: A = P rows i (j=0..31), B = V^T cols d
      const bf16x8 pa = *(const bf16x8*)&Ps[m * 32 + ((q ^ m3) * 8)];
      __builtin_amdgcn_s_setprio(1);
#pragma unroll
      for (int dt = 0; dt < 4; ++dt) {
        const bf16x8 va = *(const bf16x8*)&Vs[p][(dt * 16 + m) * 32 + ((q ^ m3) * 8)];
        o[it][dt] = mfma16(pa, va, o[it][dt]);
      }
      __builtin_amdgcn_s_setprio(0);
    }
    __syncthreads();  // Ks/Vs[p] reads done; prefetch (p^1) drained
  }

  // ---- epilogue: reduce l over q-lanes (lane holds row i = it*16+m) ----
#pragma unroll
  for (int it = 0; it < 2; ++it) {
    float t = l[it];
    t += __shfl_xor(t, 16, 64);
    t += __shfl_xor(t, 32, 64);
    l[it] = 1.0f / t;
  }
  const int colb = h * 64;
#pragma unroll
  for (int it = 0; it < 2; ++it) {
    // broadcast 1/l to o's row layout (row = q*4+r): pull from lane m = q*4+r
    float lr[4];
#pragma unroll
    for (int r = 0; r < 4; ++r) lr[r] = __shfl(l[it], q * 4 + r, 16);
#pragma unroll
    for (int dt = 0; dt < 4; ++dt)
#pragma unroll
      for (int r = 0; r < 4; ++r) {
        const int row = i0w + it * 16 + q * 4 + r;
        const size_t addr = ((size_t)b * 512 + row) * 512 + colb + dt * 16 + m;
        const float gate = bf2f(G[addr]);
        G[addr] = f2bf(o[it][dt][r] * lr[r] * gate);
      }
  }
}

// ---------------------------------------------------------------------------
// GEMM3: out = OG[32768,512] @ Wo + bo   (B^T = WoT[256][512]); fp32 output.
// Swapped MFMA operands -> f32x4 (16B) stores.
// ---------------------------------------------------------------------------
__global__ __launch_bounds__(256, 2) void gemm_og(
    const short* __restrict__ A, const short* __restrict__ Bt,
    const float* __restrict__ bo, float* __restrict__ out)
{
  __shared__ __align__(16) short As[128 * 32];
  __shared__ __align__(16) short Bs[128 * 32];
  const int tid = threadIdx.x;
  const int w = tid >> 6, lane = tid & 63;
  const int m = lane & 15, q = lane >> 4;
  const int n0 = blockIdx.x * 128, m0 = blockIdx.y * 128;
  const int ric = lane >> 2, cslot = lane & 3;
  const int csw = cslot ^ ((ric >> 1) & 3);
  const int wr = (w >> 1) * 64, wc = (w & 1) * 64;
  const int rsw = (m >> 1) & 3;
  f32x4 acc[4][4] = {};
  for (int k0 = 0; k0 < INNER_; k0 += 32) {
    __syncthreads();
#pragma unroll
    for (int s = 0; s < 2; ++s) {
      const int rr = w * 32 + s * 16;
      cp16(A  + (size_t)(m0 + rr + ric) * INNER_ + (k0 + csw * 8), &As[rr * 32]);
      cp16(Bt + (size_t)(n0 + rr + ric) * INNER_ + (k0 + csw * 8), &Bs[rr * 32]);
    }
    __syncthreads();
    bf16x8 af[4], bfv[4];
#pragma unroll
    for (int t = 0; t < 4; ++t) {
      af[t]  = *(const bf16x8*)&As[(wr + t * 16 + m) * 32 + ((q ^ rsw) * 8)];
      bfv[t] = *(const bf16x8*)&Bs[(wc + t * 16 + m) * 32 + ((q ^ rsw) * 8)];
    }
#pragma unroll
    for (int ti = 0; ti < 4; ++ti)
#pragma unroll
      for (int tj = 0; tj < 4; ++tj)
        acc[ti][tj] = mfma16(bfv[tj], af[ti], acc[ti][tj]);   // transposed C
  }
#pragma unroll
  for (int ti = 0; ti < 4; ++ti) {
    const int row = m0 + wr + ti * 16 + m;       // one output row per lane
#pragma unroll
    for (int tj = 0; tj < 4; ++tj) {
      const int c0 = n0 + wc + tj * 16 + q * 4;  // 4 consecutive out-columns
      const f32x4 bo4 = *(const f32x4*)&bo[c0];
      f32x4 v;
#pragma unroll
      for (int r = 0; r < 4; ++r) v[r] = acc[ti][tj][r] + bo4[r];
      *(f32x4*)&out[(size_t)row * 256 + c0] = v;
    }
  }
}

// ---------------------------------------------------------------------------
extern "C" void kernel_launch(void* const* d_in, const int* in_sizes, int n_in,
                              void* d_out, int out_size, void* d_ws, size_t ws_size,
                              hipStream_t stream)
{
  (void)in_sizes; (void)n_in; (void)out_size; (void)ws_size;
  const float* x    = (const float*)d_in[0];
  const int*   mask = (const int*)d_in[1];
  const float* bias = (const float*)d_in[2];
  const float* Wq   = (const float*)d_in[3];
  const float* Wkv  = (const float*)d_in[4];
  const float* Wo   = (const float*)d_in[5];
  const float* bo   = (const float*)d_in[6];
  const float* Wg   = (const float*)d_in[7];
  const float* bg   = (const float*)d_in[8];
  float* out = (float*)d_out;

  char* ws = (char*)d_ws;
  size_t off = 0;
  short* Wt1   = (short*)(ws + off); off += (size_t)2048 * 256 * 2;         // 1.0 MiB
  short* WoT   = (short*)(ws + off); off += (size_t)256 * 512 * 2;          // 0.25 MiB
  short* xb    = (short*)(ws + off); off += (size_t)32768 * 256 * 2;        // 16 MiB
  short* Qb    = (short*)(ws + off); off += (size_t)B_ * H_ * N_ * DH_ * 2; // 32 MiB
  short* Kb    = (short*)(ws + off); off += (size_t)B_ * H_ * N_ * DH_ * 2; // 32 MiB
  short* Vt    = (short*)(ws + off); off += (size_t)B_ * H_ * DH_ * N_ * 2; // 32 MiB
  short* G     = (short*)(ws + off); off += (size_t)B_ * N_ * INNER_ * 2;   // 32 MiB
  float* biasS = (float*)(ws + off); off += (size_t)H_ * N_ * N_ * 4;       // 8 MiB
  float* maskF = (float*)(ws + off); off += (size_t)B_ * N_ * 4;            // 128 KiB

  prep_k<<<(PREP_TOT + 255) / 256, 256, 0, stream>>>(x, Wq, Wkv, Wg, Wo, bias, mask,
                                                     Wt1, WoT, xb, biasS, maskF);
  gemm_qkvg<<<dim3(16, 256), 256, 0, stream>>>(xb, Wt1, bg, Qb, Kb, Vt, G);
  attn_k<<<dim3(8, 4, 64), 256, 0, stream>>>(Qb, Kb, Vt, biasS, maskF, G);
  gemm_og<<<dim3(2, 256), 256, 0, stream>>>(G, WoT, bo, out);
}

// Round 5
// 307.761 us; speedup vs baseline: 2.2943x; 1.0042x over previous
//
#include <hip/hip_runtime.h>
#include <stdint.h>

// Problem constants
#define B_    64
#define N_    512
#define DIM_  256
#define H_    8
#define DH_   64
#define INNER_ 512

typedef __attribute__((ext_vector_type(8))) short bf16x8;
typedef __attribute__((ext_vector_type(4))) float f32x4;
typedef __attribute__((ext_vector_type(4))) short s16x4;

typedef const __attribute__((address_space(1))) void* gas_ptr;
typedef __attribute__((address_space(3))) void* las_ptr;

__device__ __forceinline__ short f2bf(float f) {
  unsigned int u = __float_as_uint(f);
  u += 0x7fffu + ((u >> 16) & 1u);          // RNE
  return (short)(u >> 16);
}
__device__ __forceinline__ float bf2f(short s) {
  return __uint_as_float(((unsigned int)(unsigned short)s) << 16);
}
__device__ __forceinline__ void cp16(const void* g, void* l) {
  __builtin_amdgcn_global_load_lds((gas_ptr)g, (las_ptr)l, 16, 0, 0);
}
__device__ __forceinline__ f32x4 mfma16(bf16x8 a, bf16x8 b, f32x4 c) {
  return __builtin_amdgcn_mfma_f32_16x16x32_bf16(a, b, c, 0, 0, 0);
}

// ---------------------------------------------------------------------------
// Prep: fp32 -> bf16 edge conversions (+ scaled bias copy, float mask).
// ---------------------------------------------------------------------------
#define PREP_WT1  (2048 * 256)
#define PREP_WOT  (256 * 512)
#define PREP_X    (32768 * 256)
#define PREP_BIAS (8 * 512 * 512)
#define PREP_MASK (64 * 512)
#define PREP_TOT  (PREP_WT1 + PREP_WOT + PREP_X + PREP_BIAS + PREP_MASK)

__global__ void prep_k(const float* __restrict__ x,
                       const float* __restrict__ Wq, const float* __restrict__ Wkv,
                       const float* __restrict__ Wg, const float* __restrict__ Wo,
                       const float* __restrict__ bias, const int* __restrict__ mask,
                       short* __restrict__ Wt1, short* __restrict__ WoT,
                       short* __restrict__ xb, float* __restrict__ biasS,
                       float* __restrict__ maskF)
{
  const int idx = blockIdx.x * 256 + threadIdx.x;
  if (idx < PREP_WT1) {
    const int n = idx >> 8, k = idx & 255;
    float v;
    if (n < 512)        v = Wq[k * 512 + n];
    else if (n < 1536)  v = Wkv[k * 1024 + (n - 512)];   // K cols then V cols
    else                v = Wg[k * 512 + (n - 1536)];
    Wt1[idx] = f2bf(v);
  } else if (idx < PREP_WT1 + PREP_WOT) {
    const int j = idx - PREP_WT1;
    const int n = j >> 9, k = j & 511;
    WoT[j] = f2bf(Wo[k * 256 + n]);
  } else if (idx < PREP_WT1 + PREP_WOT + PREP_X) {
    const int j = idx - (PREP_WT1 + PREP_WOT);
    xb[j] = f2bf(x[j]);
  } else if (idx < PREP_WT1 + PREP_WOT + PREP_X + PREP_BIAS) {
    const int j = idx - (PREP_WT1 + PREP_WOT + PREP_X);
    biasS[j] = bias[j] * 1.4426950408889634f;            // coalesced scaled copy
  } else if (idx < PREP_TOT) {
    const int j = idx - (PREP_WT1 + PREP_WOT + PREP_X + PREP_BIAS);
    maskF[j] = mask[j] ? 1.0f : 0.0f;
  }
}

// ---------------------------------------------------------------------------
// GEMM1: C = xb[32768,256] @ Wt1^T  (N=2048 fused Q|K|V|G), all bf16.
// Q/K/G regions use SWAPPED MFMA operands (transposed C: lane holds 4
// consecutive n-columns of one x-row) -> s16x4 stores. V keeps original
// orientation for its [d][n] transposed store. (Frozen this round.)
// ---------------------------------------------------------------------------
__global__ __launch_bounds__(256, 2) void gemm_qkvg(
    const short* __restrict__ X, const short* __restrict__ Wt,
    const float* __restrict__ bg,
    short* __restrict__ Q, short* __restrict__ Kb,
    short* __restrict__ Vt, short* __restrict__ G)
{
  __shared__ __align__(16) short As[128 * 32];
  __shared__ __align__(16) short Bs[128 * 32];
  const int tid = threadIdx.x;
  const int w = tid >> 6, lane = tid & 63;
  const int m = lane & 15, q = lane >> 4;
  const int n0 = blockIdx.x * 128, m0 = blockIdx.y * 128;
  const int region = blockIdx.x >> 2;           // 0=Q 1=K 2=V 3=G
  const bool vreg = (region == 2);
  const int ric = lane >> 2, cslot = lane & 3;
  const int csw = cslot ^ ((ric >> 1) & 3);
  const int wr = (w >> 1) * 64, wc = (w & 1) * 64;
  const int rsw = (m >> 1) & 3;
  f32x4 acc[4][4] = {};
  for (int k0 = 0; k0 < DIM_; k0 += 32) {
    __syncthreads();
#pragma unroll
    for (int s = 0; s < 2; ++s) {
      const int rr = w * 32 + s * 16;
      cp16(X  + (size_t)(m0 + rr + ric) * DIM_ + (k0 + csw * 8), &As[rr * 32]);
      cp16(Wt + (size_t)(n0 + rr + ric) * DIM_ + (k0 + csw * 8), &Bs[rr * 32]);
    }
    __syncthreads();
    bf16x8 af[4], bfv[4];
#pragma unroll
    for (int t = 0; t < 4; ++t) {
      af[t]  = *(const bf16x8*)&As[(wr + t * 16 + m) * 32 + ((q ^ rsw) * 8)];
      bfv[t] = *(const bf16x8*)&Bs[(wc + t * 16 + m) * 32 + ((q ^ rsw) * 8)];
    }
    if (vreg) {
#pragma unroll
      for (int ti = 0; ti < 4; ++ti)
#pragma unroll
        for (int tj = 0; tj < 4; ++tj)
          acc[ti][tj] = mfma16(af[ti], bfv[tj], acc[ti][tj]);
    } else {
#pragma unroll
      for (int ti = 0; ti < 4; ++ti)
#pragma unroll
        for (int tj = 0; tj < 4; ++tj)
          acc[ti][tj] = mfma16(bfv[tj], af[ti], acc[ti][tj]);  // transposed C
    }
  }
  if (vreg) {                                    // V -> transposed [B,H,DH,N]
    const int cb = (n0 & 511) + wc;
#pragma unroll
    for (int ti = 0; ti < 4; ++ti) {
      const int mgb = m0 + wr + ti * 16 + q * 4;
      const int b = mgb >> 9, n = mgb & 511;
#pragma unroll
      for (int tj = 0; tj < 4; ++tj) {
        const int c = cb + tj * 16 + m;
        const int h = c >> 6, d = c & 63;
        s16x4 st;
#pragma unroll
        for (int r = 0; r < 4; ++r) st[r] = f2bf(acc[ti][tj][r]);
        *(s16x4*)&Vt[((size_t)(b * 8 + h) * 64 + d) * 512 + n] = st;
      }
    }
  } else {                                       // Q / K / G: transposed C
#pragma unroll
    for (int ti = 0; ti < 4; ++ti) {
      const int xrow = m0 + wr + ti * 16 + m;    // one x-row per lane
      const int b = xrow >> 9, n = xrow & 511;
#pragma unroll
      for (int tj = 0; tj < 4; ++tj) {
        const int cvec = (n0 & 511) + wc + tj * 16 + q * 4;  // 4 consecutive cols
        if (region == 3) {                       // gates = x@Wg + bg
          const f32x4 bg4 = *(const f32x4*)&bg[cvec];
          s16x4 st;
#pragma unroll
          for (int r = 0; r < 4; ++r) st[r] = f2bf(acc[ti][tj][r] + bg4[r]);
          *(s16x4*)&G[(size_t)xrow * 512 + cvec] = st;
        } else {
          const int h = cvec >> 6, d0 = cvec & 63;
          s16x4 st;
#pragma unroll
          for (int r = 0; r < 4; ++r) st[r] = f2bf(acc[ti][tj][r]);
          short* dst = (region == 0) ? Q : Kb;
          *(s16x4*)&dst[((size_t)(b * 8 + h) * 512 + n) * 64 + d0] = st;
        }
      }
    }
  }
}

// ---------------------------------------------------------------------------
// Attention, flash-style, TRANSPOSED score MFMA (S^T = K·Q^T). KVBLK=32.
// NEW: Vs/Ps swizzle upgraded from (row&3) to ((row ^ row>>2)&3).
// Bank algebra: 64B rows put the row term at (m&1)*16 (mod 32 words); the
// old swizzle only mixed m's low 2 bits -> lanes m,m+4,m+8,m+12 shared a
// bank quad = 4-way conflict on every Vs/Ps access (11.5M conflict-cycles,
// ~18% of kernel). New swizzle spreads the four m-groups -> 2-way (free).
// Staging compensates via pre-swizzled global chunk (cp16 dest stays linear).
// ---------------------------------------------------------------------------
__global__ __launch_bounds__(256, 4) void attn_k(
    const short* __restrict__ Q, const short* __restrict__ K,
    const short* __restrict__ Vt, const float* __restrict__ biasS,
    const float* __restrict__ maskF, short* __restrict__ G)
{
  __shared__ __align__(16) short Ks[2][32 * 64];   // [j][d], xor-swizzled by j&7
  __shared__ __align__(16) short Vs[2][64 * 32];   // [d][j], slot-xor (d^d>>2)&3
  __shared__ __align__(16) short Pall[4][16 * 32]; // per-wave, slot-xor (i^i>>2)&3
  const int tid = threadIdx.x;
  const int w = tid >> 6, lane = tid & 63;
  const int m = lane & 15, q = lane >> 4;
  const int m7 = m & 7;
  const int vsw = (m ^ (m >> 2)) & 3;              // bank-spread swizzle for 64B rows
  const int h = blockIdx.x, iq = blockIdx.y, b = blockIdx.z;
  const int i0w = iq * 128 + w * 32;               // this wave's first Q row
  const size_t bh = (size_t)b * 8 + h;
  const short* Qp = Q + (bh * 512 + i0w) * 64;
  const short* Kp = K + bh * 512 * 64;
  const short* Vp = Vt + bh * 64 * 512;
  const float* mkp = maskF + b * 512;
  short* Ps = Pall[w];

  // K staging: wave w stages rows w*8..w*8+7 (128B rows, 8 chunks of 8 shorts)
  const int srow = lane >> 3;                      // 0..7
  const int gchunk = (lane & 7) ^ srow;            // global d-chunk (xor by row&7)
  // V staging: wave w stages rows w*16..w*16+15 (64B rows, 4 chunks of 8)
  const int vrow = lane >> 2;                      // 0..15
  const int gchunkV = (lane & 3) ^ ((vrow ^ (vrow >> 2)) & 3);

  // Q frags (B-operand): lane holds Q[i=m][d=q*8+jj]
  bf16x8 qf[2][2];
#pragma unroll
  for (int it = 0; it < 2; ++it) {
    qf[it][0] = *(const bf16x8*)&Qp[(it * 16 + m) * 64 + q * 8];
    qf[it][1] = *(const bf16x8*)&Qp[(it * 16 + m) * 64 + 32 + q * 8];
  }
  float miF[2];
#pragma unroll
  for (int it = 0; it < 2; ++it) miF[it] = mkp[i0w + it * 16 + m];

  // stage chunk 0 (1 cp16 for K + 1 for V per wave)
  cp16(Kp + (size_t)(w * 8 + srow) * 64 + gchunk * 8, &Ks[0][w * 8 * 64]);
  cp16(Vp + (size_t)(w * 16 + vrow) * 512 + gchunkV * 8, &Vs[0][w * 16 * 32]);

  f32x4 o[2][4] = {};
  float l[2] = {0.f, 0.f};
  __syncthreads();                                 // chunk 0 staged

  const float SCL = 0.125f * 1.4426950408889634f;  // scale * log2(e)
  for (int c = 0; c < 16; ++c) {
    const int p = c & 1;
    if (c < 15) {                                  // prefetch next chunk
      const int jn = (c + 1) * 32;
      cp16(Kp + (size_t)(jn + w * 8 + srow) * 64 + gchunk * 8, &Ks[p ^ 1][w * 8 * 64]);
      cp16(Vp + (size_t)(w * 16 + vrow) * 512 + jn + gchunkV * 8, &Vs[p ^ 1][w * 16 * 32]);
    }
    // mask (f32x4 per jt): j = c*32 + jt*16 + q*4 + r
    f32x4 mjf[2];
#pragma unroll
    for (int jt = 0; jt < 2; ++jt)
      mjf[jt] = *(const f32x4*)&mkp[c * 32 + jt * 16 + q * 4];

    // QK^T (transposed): lane holds S[i = it*16+m][j = c*32 + jt*16 + q*4 + r]
    f32x4 s[2][2];
    __builtin_amdgcn_s_setprio(1);
#pragma unroll
    for (int jt = 0; jt < 2; ++jt) {
      const bf16x8 ka = *(const bf16x8*)&Ks[p][(jt * 16 + m) * 64 + ((q ^ m7) * 8)];
      const bf16x8 kb = *(const bf16x8*)&Ks[p][(jt * 16 + m) * 64 + (((4 + q) ^ m7) * 8)];
#pragma unroll
      for (int it = 0; it < 2; ++it) {
        f32x4 a = {};
        a = mfma16(ka, qf[it][0], a);
        s[it][jt] = mfma16(kb, qf[it][1], a);
      }
    }
    __builtin_amdgcn_s_setprio(0);
#pragma unroll
    for (int it = 0; it < 2; ++it) {
      // bias (fp32, prescaled by log2e, original [h][i][j] layout)
      const float* bp = biasS + ((size_t)h * 512 + i0w + it * 16 + m) * 512 + c * 32;
      f32x4 bv[2];
#pragma unroll
      for (int jt = 0; jt < 2; ++jt)
        bv[jt] = *(const f32x4*)&bp[jt * 16 + q * 4];
      // softmax terms -> packed b64 P writes (4 consecutive j per lane)
#pragma unroll
      for (int jt = 0; jt < 2; ++jt) {
        s16x4 st;
#pragma unroll
        for (int r = 0; r < 4; ++r) {
          const float v = fmaf(s[it][jt][r], SCL, bv[jt][r]);
          float e = exp2f(v) * mjf[jt][r];
          e = (miF[it] != 0.0f) ? e : 1.0f;        // fully-masked row -> uniform
          const unsigned u = __float_as_uint(e);
          st[r] = (short)(u >> 16);                // trunc pack
          l[it] += __uint_as_float(u & 0xffff0000u); // == stored P
        }
        *(s16x4*)&Ps[m * 32 + (((jt * 2 + (q >> 1)) ^ vsw) * 8) + (q & 1) * 4] = st;
      }
      // PV for this i-tile: A = P rows i (j=0..31), B = V^T cols d
      const bf16x8 pa = *(const bf16x8*)&Ps[m * 32 + ((q ^ vsw) * 8)];
      __builtin_amdgcn_s_setprio(1);
#pragma unroll
      for (int dt = 0; dt < 4; ++dt) {
        const bf16x8 va = *(const bf16x8*)&Vs[p][(dt * 16 + m) * 32 + ((q ^ vsw) * 8)];
        o[it][dt] = mfma16(pa, va, o[it][dt]);
      }
      __builtin_amdgcn_s_setprio(0);
    }
    __syncthreads();  // Ks/Vs[p] reads done; prefetch (p^1) drained
  }

  // ---- epilogue: reduce l over q-lanes (lane holds row i = it*16+m) ----
#pragma unroll
  for (int it = 0; it < 2; ++it) {
    float t = l[it];
    t += __shfl_xor(t, 16, 64);
    t += __shfl_xor(t, 32, 64);
    l[it] = 1.0f / t;
  }
  const int colb = h * 64;
#pragma unroll
  for (int it = 0; it < 2; ++it) {
    // broadcast 1/l to o's row layout (row = q*4+r): pull from lane m = q*4+r
    float lr[4];
#pragma unroll
    for (int r = 0; r < 4; ++r) lr[r] = __shfl(l[it], q * 4 + r, 16);
#pragma unroll
    for (int dt = 0; dt < 4; ++dt)
#pragma unroll
      for (int r = 0; r < 4; ++r) {
        const int row = i0w + it * 16 + q * 4 + r;
        const size_t addr = ((size_t)b * 512 + row) * 512 + colb + dt * 16 + m;
        const float gate = bf2f(G[addr]);
        G[addr] = f2bf(o[it][dt][r] * lr[r] * gate);
      }
  }
}

// ---------------------------------------------------------------------------
// GEMM3: out = OG[32768,512] @ Wo + bo   (B^T = WoT[256][512]); fp32 output.
// NEW: 64x128 tiles, grid (2, 512) = 1024 blocks (was 512) -> 4 blocks/CU
// (was 2, 25% occupancy ceiling). LDS 12KB. Swapped MFMA -> f32x4 stores.
// ---------------------------------------------------------------------------
__global__ __launch_bounds__(256, 2) void gemm_og(
    const short* __restrict__ A, const short* __restrict__ Bt,
    const float* __restrict__ bo, float* __restrict__ out)
{
  __shared__ __align__(16) short As[64 * 32];
  __shared__ __align__(16) short Bs[128 * 32];
  const int tid = threadIdx.x;
  const int w = tid >> 6, lane = tid & 63;
  const int m = lane & 15, q = lane >> 4;
  const int n0 = blockIdx.x * 128, m0 = blockIdx.y * 64;
  const int ric = lane >> 2, cslot = lane & 3;
  const int csw = cslot ^ ((ric >> 1) & 3);
  const int wr = (w >> 1) * 32, wc = (w & 1) * 64;
  const int rsw = (m >> 1) & 3;
  f32x4 acc[2][4] = {};
  for (int k0 = 0; k0 < INNER_; k0 += 32) {
    __syncthreads();
    // As: 64 rows, 1 cp16/thread (wave w stages rows w*16..w*16+15)
    cp16(A + (size_t)(m0 + w * 16 + ric) * INNER_ + (k0 + csw * 8), &As[w * 16 * 32]);
    // Bs: 128 rows, 2 cp16/thread
#pragma unroll
    for (int s = 0; s < 2; ++s) {
      const int rr = w * 32 + s * 16;
      cp16(Bt + (size_t)(n0 + rr + ric) * INNER_ + (k0 + csw * 8), &Bs[rr * 32]);
    }
    __syncthreads();
    bf16x8 af[2], bfv[4];
#pragma unroll
    for (int t = 0; t < 2; ++t)
      af[t]  = *(const bf16x8*)&As[(wr + t * 16 + m) * 32 + ((q ^ rsw) * 8)];
#pragma unroll
    for (int t = 0; t < 4; ++t)
      bfv[t] = *(const bf16x8*)&Bs[(wc + t * 16 + m) * 32 + ((q ^ rsw) * 8)];
#pragma unroll
    for (int ti = 0; ti < 2; ++ti)
#pragma unroll
      for (int tj = 0; tj < 4; ++tj)
        acc[ti][tj] = mfma16(bfv[tj], af[ti], acc[ti][tj]);   // transposed C
  }
#pragma unroll
  for (int ti = 0; ti < 2; ++ti) {
    const int row = m0 + wr + ti * 16 + m;       // one output row per lane
#pragma unroll
    for (int tj = 0; tj < 4; ++tj) {
      const int c0 = n0 + wc + tj * 16 + q * 4;  // 4 consecutive out-columns
      const f32x4 bo4 = *(const f32x4*)&bo[c0];
      f32x4 v;
#pragma unroll
      for (int r = 0; r < 4; ++r) v[r] = acc[ti][tj][r] + bo4[r];
      *(f32x4*)&out[(size_t)row * 256 + c0] = v;
    }
  }
}

// ---------------------------------------------------------------------------
extern "C" void kernel_launch(void* const* d_in, const int* in_sizes, int n_in,
                              void* d_out, int out_size, void* d_ws, size_t ws_size,
                              hipStream_t stream)
{
  (void)in_sizes; (void)n_in; (void)out_size; (void)ws_size;
  const float* x    = (const float*)d_in[0];
  const int*   mask = (const int*)d_in[1];
  const float* bias = (const float*)d_in[2];
  const float* Wq   = (const float*)d_in[3];
  const float* Wkv  = (const float*)d_in[4];
  const float* Wo   = (const float*)d_in[5];
  const float* bo   = (const float*)d_in[6];
  const float* Wg   = (const float*)d_in[7];
  const float* bg   = (const float*)d_in[8];
  float* out = (float*)d_out;

  char* ws = (char*)d_ws;
  size_t off = 0;
  short* Wt1   = (short*)(ws + off); off += (size_t)2048 * 256 * 2;         // 1.0 MiB
  short* WoT   = (short*)(ws + off); off += (size_t)256 * 512 * 2;          // 0.25 MiB
  short* xb    = (short*)(ws + off); off += (size_t)32768 * 256 * 2;        // 16 MiB
  short* Qb    = (short*)(ws + off); off += (size_t)B_ * H_ * N_ * DH_ * 2; // 32 MiB
  short* Kb    = (short*)(ws + off); off += (size_t)B_ * H_ * N_ * DH_ * 2; // 32 MiB
  short* Vt    = (short*)(ws + off); off += (size_t)B_ * H_ * DH_ * N_ * 2; // 32 MiB
  short* G     = (short*)(ws + off); off += (size_t)B_ * N_ * INNER_ * 2;   // 32 MiB
  float* biasS = (float*)(ws + off); off += (size_t)H_ * N_ * N_ * 4;       // 8 MiB
  float* maskF = (float*)(ws + off); off += (size_t)B_ * N_ * 4;            // 128 KiB

  prep_k<<<(PREP_TOT + 255) / 256, 256, 0, stream>>>(x, Wq, Wkv, Wg, Wo, bias, mask,
                                                     Wt1, WoT, xb, biasS, maskF);
  gemm_qkvg<<<dim3(16, 256), 256, 0, stream>>>(xb, Wt1, bg, Qb, Kb, Vt, G);
  attn_k<<<dim3(8, 4, 64), 256, 0, stream>>>(Qb, Kb, Vt, biasS, maskF, G);
  gemm_og<<<dim3(2, 512), 256, 0, stream>>>(G, WoT, bo, out);
}